// Round 3
// baseline (422.048 us; speedup 1.0000x reference)
//
#include <hip/hip_runtime.h>
#include <hip/hip_bf16.h>

#define B   2
#define NN_ 5000
#define NE_ 160000
#define F   128
#define HID 128
#define ED  16
#define IN_EDGE 288   // 2*F + 16 + ED

typedef __bf16 bf16x8 __attribute__((ext_vector_type(8)));
typedef __bf16 bf16x4 __attribute__((ext_vector_type(4)));
typedef float  f32x4  __attribute__((ext_vector_type(4)));

#define XSS 296   // xs row stride (bf16): 16B-aligned rows, 2-way banks (free)
#define MS  136   // mid-buffer row stride
#define LCAP 1024 // per-block edge-list LDS capacity (8 nodes, deg~32 each)

// ---------------- weight pack: row-major fp32 [K][N] -> bf16 MFMA B-fragments ----
__global__ void pack_weights(const float* __restrict__ We1, const float* __restrict__ We2,
                             const float* __restrict__ Wc1, const float* __restrict__ Wc2,
                             __bf16* __restrict__ pw1, __bf16* __restrict__ pw2,
                             __bf16* __restrict__ pwc1, __bf16* __restrict__ pwc2)
{
    int idx = blockIdx.x * 256 + threadIdx.x;   // 0 .. 71679
    const float* W; __bf16* P; int KT, Nr, local;
    if (idx < 36864)      { W = We1; P = pw1;  KT = 9; Nr = 128; local = idx; }
    else if (idx < 53248) { W = We2; P = pw2;  KT = 4; Nr = 128; local = idx - 36864; }
    else if (idx < 69632) { W = Wc1; P = pwc1; KT = 4; Nr = 128; local = idx - 53248; }
    else                  { W = Wc2; P = pwc2; KT = 4; Nr = 4;   local = idx - 69632; }
    int j = local & 7, lane = (local >> 3) & 63, rest = local >> 9;
    int kt = rest % KT, nt = rest / KT;
    int k = kt * 32 + (lane >> 4) * 8 + j;
    int n = nt * 16 + (lane & 15);
    float v = (n < Nr) ? W[k * Nr + n] : 0.f;
    P[local] = (__bf16)v;
}

// ---------------- CSR build ----------------
__global__ void hist_kernel(const int* __restrict__ ei, int* __restrict__ csr_cnt)
{
    int i = blockIdx.x * 256 + threadIdx.x;
    if (i < NE_) atomicAdd(&csr_cnt[ei[i]], 1);
}

__global__ void scan_kernel(const int* __restrict__ csr_cnt,
                            int* __restrict__ csr_off, int* __restrict__ csr_pos)
{
    __shared__ int part[256];
    const int t = threadIdx.x;
    int sum = 0;
    #pragma unroll
    for (int j = 0; j < 20; j++) {
        int idx = t * 20 + j;
        if (idx < NN_) sum += csr_cnt[idx];
    }
    part[t] = sum;
    __syncthreads();
    if (t == 0) {
        int run = 0;
        for (int i = 0; i < 256; i++) { int v = part[i]; part[i] = run; run += v; }
    }
    __syncthreads();
    int run = part[t];
    #pragma unroll
    for (int j = 0; j < 20; j++) {
        int idx = t * 20 + j;
        if (idx < NN_) { csr_off[idx] = run; csr_pos[idx] = run; run += csr_cnt[idx]; }
    }
    if (t == 0) csr_off[NN_] = NE_;
}

__global__ void bucket_kernel(const int* __restrict__ ei,
                              int* __restrict__ csr_pos, int* __restrict__ bucket)
{
    int i = blockIdx.x * 256 + threadIdx.x;
    if (i < NE_) { int p = atomicAdd(&csr_pos[ei[i]], 1); bucket[p] = i; }
}

// ---------------- edge kernel: gather -> 4-layer MFMA MLP -> epilogue ----------
template<bool CSR>
__global__ __launch_bounds__(256) void edge_kernel(
    const float* __restrict__ h, const float* __restrict__ coord,
    const int* __restrict__ ei, const float* __restrict__ ea,
    const float* __restrict__ be1, const float* __restrict__ be2,
    const float* __restrict__ bc1,
    const __bf16* __restrict__ pw1, const __bf16* __restrict__ pw2,
    const __bf16* __restrict__ pwc1, const __bf16* __restrict__ pwc2,
    float* __restrict__ agg_h, float* __restrict__ agg_c, float* __restrict__ cnt,
    unsigned* __restrict__ ef_g, float* __restrict__ trans_g)
{
    __shared__ __align__(16) __bf16 R[18944];        // xs[64][296] | buf1/buf2[64][136]
    __shared__ float cds[64][12];
    __shared__ int rs[64], cs[64];

    const int t = threadIdx.x;
    const int b = blockIdx.y;
    const int e0 = blockIdx.x * 64;
    const int lane = t & 63, wave = t >> 6;
    const int quad = lane >> 4, c = lane & 15;

    if (t < 64) { rs[t] = ei[e0 + t]; cs[t] = ei[NE_ + e0 + t]; }
    __syncthreads();

    // ---- stage xs = [h_row | h_col | radial | edge_attr] as bf16 ----
    const float* hb = h + (size_t)b * NN_ * F;
    #pragma unroll
    for (int eb = 0; eb < 64; eb += 4) {
        int e = eb + wave;
        int node, dst;
        if (lane < 32) { node = rs[e]; dst = lane * 4; }
        else           { node = cs[e]; dst = F + (lane - 32) * 4; }
        float4 v = *(const float4*)(hb + (size_t)node * F + (lane & 31) * 4);
        bf16x4 bv = { (__bf16)v.x, (__bf16)v.y, (__bf16)v.z, (__bf16)v.w };
        *(bf16x4*)&R[e * XSS + dst] = bv;
    }
    if (t < 64) {
        int e = t;
        const float* cr = coord + ((size_t)b * NN_ + rs[e]) * 12;
        const float* cc = coord + ((size_t)b * NN_ + cs[e]) * 12;
        float cd[12];
        #pragma unroll
        for (int j = 0; j < 12; j++) { cd[j] = cr[j] - cc[j]; cds[e][j] = cd[j]; }
        float prod[16]; float ss = 0.f;
        #pragma unroll
        for (int j = 0; j < 4; j++)
            #pragma unroll
            for (int k = 0; k < 4; k++) {
                float p = cd[j*3]*cd[k*3] + cd[j*3+1]*cd[k*3+1] + cd[j*3+2]*cd[k*3+2];
                prod[j*4 + k] = p; ss += p * p;
            }
        float inv = 1.0f / fmaxf(sqrtf(ss), 1e-12f);
        #pragma unroll
        for (int j = 0; j < 16; j++) R[e * XSS + 2*F + j] = (__bf16)(prod[j] * inv);
        const float* eap = ea + (size_t)(e0 + e) * ED;
        #pragma unroll
        for (int j = 0; j < 16; j++) R[e * XSS + 2*F + 16 + j] = (__bf16)eap[j];
    }
    __syncthreads();

    const bf16x8* pw1v  = (const bf16x8*)pw1;
    const bf16x8* pw2v  = (const bf16x8*)pw2;
    const bf16x8* pwc1v = (const bf16x8*)pwc1;
    const bf16x8* pwc2v = (const bf16x8*)pwc2;
    __bf16* buf1 = R;
    __bf16* buf2 = R + 8704;   // 64*136

    // ---- layer e1: x(288) @ We1 ----
    f32x4 acc[8];
    #pragma unroll
    for (int nt = 0; nt < 8; nt++) acc[nt] = (f32x4){0.f, 0.f, 0.f, 0.f};
    for (int kt = 0; kt < 9; kt++) {
        bf16x8 a = *(const bf16x8*)&R[(wave*16 + c) * XSS + kt*32 + quad*8];
        #pragma unroll
        for (int nt = 0; nt < 8; nt++)
            acc[nt] = __builtin_amdgcn_mfma_f32_16x16x32_bf16(a, pw1v[(nt*9 + kt)*64 + lane], acc[nt], 0, 0, 0);
    }
    __syncthreads();   // xs dead; R reusable
    #pragma unroll
    for (int nt = 0; nt < 8; nt++)
        #pragma unroll
        for (int i = 0; i < 4; i++) {
            float v = fmaxf(acc[nt][i] + be1[nt*16 + c], 0.f);
            buf1[(wave*16 + quad*4 + i) * MS + nt*16 + c] = (__bf16)v;
        }
    __syncthreads();

    // ---- layer e2: h1 @ We2 -> ef ----
    f32x4 acc2[8];
    #pragma unroll
    for (int nt = 0; nt < 8; nt++) acc2[nt] = (f32x4){0.f, 0.f, 0.f, 0.f};
    for (int kt = 0; kt < 4; kt++) {
        bf16x8 a = *(const bf16x8*)&buf1[(wave*16 + c) * MS + kt*32 + quad*8];
        #pragma unroll
        for (int nt = 0; nt < 8; nt++)
            acc2[nt] = __builtin_amdgcn_mfma_f32_16x16x32_bf16(a, pw2v[(nt*4 + kt)*64 + lane], acc2[nt], 0, 0, 0);
    }
    int er[4];
    if constexpr (!CSR) {
        #pragma unroll
        for (int i = 0; i < 4; i++) er[i] = rs[wave*16 + quad*4 + i];
    }
    #pragma unroll
    for (int nt = 0; nt < 8; nt++)
        #pragma unroll
        for (int i = 0; i < 4; i++) {
            float v = fmaxf(acc2[nt][i] + be2[nt*16 + c], 0.f);
            if constexpr (!CSR) {
                float* aggh_b = agg_h + (size_t)b * NN_ * HID;
                atomicAdd(&aggh_b[(size_t)er[i] * HID + nt*16 + c], v);
            }
            buf2[(wave*16 + quad*4 + i) * MS + nt*16 + c] = (__bf16)v;
        }
    __syncthreads();

    // ---- coord layer c1: ef @ Wc1 ----
    f32x4 acc3[8];
    #pragma unroll
    for (int nt = 0; nt < 8; nt++) acc3[nt] = (f32x4){0.f, 0.f, 0.f, 0.f};
    for (int kt = 0; kt < 4; kt++) {
        bf16x8 a = *(const bf16x8*)&buf2[(wave*16 + c) * MS + kt*32 + quad*8];
        #pragma unroll
        for (int nt = 0; nt < 8; nt++)
            acc3[nt] = __builtin_amdgcn_mfma_f32_16x16x32_bf16(a, pwc1v[(nt*4 + kt)*64 + lane], acc3[nt], 0, 0, 0);
    }
    __syncthreads();
    #pragma unroll
    for (int nt = 0; nt < 8; nt++)
        #pragma unroll
        for (int i = 0; i < 4; i++) {
            float v = fmaxf(acc3[nt][i] + bc1[nt*16 + c], 0.f);
            buf1[(wave*16 + quad*4 + i) * MS + nt*16 + c] = (__bf16)v;
        }
    __syncthreads();

    // ---- coord layer c2: h2 @ Wc2 (128x4 zero-padded to 16 cols) ----
    f32x4 accw = (f32x4){0.f, 0.f, 0.f, 0.f};
    for (int kt = 0; kt < 4; kt++) {
        bf16x8 a = *(const bf16x8*)&buf1[(wave*16 + c) * MS + kt*32 + quad*8];
        accw = __builtin_amdgcn_mfma_f32_16x16x32_bf16(a, pwc2v[kt*64 + lane], accw, 0, 0, 0);
    }

    if constexpr (CSR) {
        const size_t bE = (size_t)b * NE_;
        // ef rows from buf2 (bf16), dword-coalesced streaming store
        #pragma unroll
        for (int erow = 0; erow < 16; erow++) {
            int e = wave * 16 + erow;
            unsigned d = *(const unsigned*)&R[8704 + e * MS + 2 * lane];
            ef_g[(bE + e0 + e) * 64 + lane] = d;
        }
        // trans = cd * w, in-place in cds, then coalesced copy
        if (c < 4) {
            #pragma unroll
            for (int i = 0; i < 4; i++) {
                int el = wave*16 + quad*4 + i;
                float w = accw[i];
                #pragma unroll
                for (int d = 0; d < 3; d++) cds[el][c*3 + d] *= w;
            }
        }
        __syncthreads();
        const float* cf = &cds[0][0];
        float* tg = trans_g + (bE + e0) * 12;
        #pragma unroll
        for (int k = 0; k < 3; k++) tg[t + k*256] = cf[t + k*256];
    } else {
        if (c < 4) {
            #pragma unroll
            for (int i = 0; i < 4; i++) {
                float w = accw[i];
                int el = wave*16 + quad*4 + i;
                float* dst = agg_c + ((size_t)b * NN_ + er[i]) * 12 + c*3;
                #pragma unroll
                for (int d = 0; d < 3; d++)
                    atomicAdd(&dst[d], cds[el][c*3 + d] * w);
            }
        }
        if (c == 0) {
            #pragma unroll
            for (int i = 0; i < 4; i++)
                atomicAdd(&cnt[b * NN_ + er[i]], 1.0f);
        }
    }
}

// ---------------- node kernel (CSR gather variant) ----------------
#define NPB 8
__global__ __launch_bounds__(128) void node_kernel_csr(
    const float* __restrict__ h, const unsigned short* __restrict__ efb,
    const int* __restrict__ bucket, const int* __restrict__ csr_off,
    const float* __restrict__ Wn1, const float* __restrict__ bn1,
    const float* __restrict__ Wn2, const float* __restrict__ bn2,
    float* __restrict__ out_h)
{
    __shared__ float zs[NPB][2 * F];
    __shared__ float h1[NPB][HID];
    __shared__ int elist[LCAP];
    __shared__ int sofs[NPB + 1];
    const int t  = threadIdx.x;
    const int b  = blockIdx.y;
    const int n0 = blockIdx.x * NPB;

    if (t < NPB + 1) sofs[t] = csr_off[n0 + t];
    #pragma unroll
    for (int i = 0; i < NPB; i++) {
        size_t base = ((size_t)b * NN_ + n0 + i);
        zs[i][t] = h[base * F + t];
    }
    __syncthreads();
    const int bse = sofs[0], total = sofs[NPB] - bse;
    for (int k = t; k < total; k += 128) {
        int v = bucket[bse + k];
        if (k < LCAP) elist[k] = v;
    }
    __syncthreads();

    // gather-aggregate ef (bf16 -> fp32 sum)
    const size_t ebase = (size_t)b * NE_;
    #pragma unroll
    for (int i = 0; i < NPB; i++) {
        int s = sofs[i] - bse, e_ = sofs[i + 1] - bse;
        float acc = 0.f;
        for (int k = s; k < e_; k++) {
            int e = (k < LCAP) ? elist[k] : bucket[bse + k];
            unsigned short u = efb[(ebase + e) * 128 + t];
            acc += __uint_as_float((unsigned)u << 16);
        }
        zs[i][F + t] = acc;
    }
    __syncthreads();

    float acc[NPB];
    #pragma unroll
    for (int i = 0; i < NPB; i++) acc[i] = bn1[t];
    for (int k = 0; k < 2 * F; k += 4) {
        float w0 = Wn1[(k+0)*HID + t], w1 = Wn1[(k+1)*HID + t];
        float w2 = Wn1[(k+2)*HID + t], w3 = Wn1[(k+3)*HID + t];
        #pragma unroll
        for (int i = 0; i < NPB; i++) {
            float4 xv = *(const float4*)&zs[i][k];
            acc[i] += xv.x*w0 + xv.y*w1 + xv.z*w2 + xv.w*w3;
        }
    }
    __syncthreads();
    #pragma unroll
    for (int i = 0; i < NPB; i++) h1[i][t] = fmaxf(acc[i], 0.f);
    __syncthreads();

    #pragma unroll
    for (int i = 0; i < NPB; i++) acc[i] = bn2[t];
    for (int k = 0; k < HID; k += 4) {
        float w0 = Wn2[(k+0)*F + t], w1 = Wn2[(k+1)*F + t];
        float w2 = Wn2[(k+2)*F + t], w3 = Wn2[(k+3)*F + t];
        #pragma unroll
        for (int i = 0; i < NPB; i++) {
            float4 xv = *(const float4*)&h1[i][k];
            acc[i] += xv.x*w0 + xv.y*w1 + xv.z*w2 + xv.w*w3;
        }
    }
    #pragma unroll
    for (int i = 0; i < NPB; i++) {
        size_t base = ((size_t)b * NN_ + n0 + i);
        out_h[base * F + t] = zs[i][t] + acc[i];
    }
}

// ---------------- node kernel (fallback: reads precomputed agg_h) ----------------
__global__ __launch_bounds__(128) void node_kernel_fb(
    const float* __restrict__ h, const float* __restrict__ agg_h,
    const float* __restrict__ Wn1, const float* __restrict__ bn1,
    const float* __restrict__ Wn2, const float* __restrict__ bn2,
    float* __restrict__ out_h)
{
    __shared__ float zs[NPB][2 * F];
    __shared__ float h1[NPB][HID];
    const int t  = threadIdx.x;
    const int b  = blockIdx.y;
    const int n0 = blockIdx.x * NPB;

    #pragma unroll
    for (int i = 0; i < NPB; i++) {
        size_t base = ((size_t)b * NN_ + n0 + i);
        zs[i][t]     = h[base * F + t];
        zs[i][F + t] = agg_h[base * HID + t];
    }
    __syncthreads();

    float acc[NPB];
    #pragma unroll
    for (int i = 0; i < NPB; i++) acc[i] = bn1[t];
    for (int k = 0; k < 2 * F; k += 4) {
        float w0 = Wn1[(k+0)*HID + t], w1 = Wn1[(k+1)*HID + t];
        float w2 = Wn1[(k+2)*HID + t], w3 = Wn1[(k+3)*HID + t];
        #pragma unroll
        for (int i = 0; i < NPB; i++) {
            float4 xv = *(const float4*)&zs[i][k];
            acc[i] += xv.x*w0 + xv.y*w1 + xv.z*w2 + xv.w*w3;
        }
    }
    __syncthreads();
    #pragma unroll
    for (int i = 0; i < NPB; i++) h1[i][t] = fmaxf(acc[i], 0.f);
    __syncthreads();

    #pragma unroll
    for (int i = 0; i < NPB; i++) acc[i] = bn2[t];
    for (int k = 0; k < HID; k += 4) {
        float w0 = Wn2[(k+0)*F + t], w1 = Wn2[(k+1)*F + t];
        float w2 = Wn2[(k+2)*F + t], w3 = Wn2[(k+3)*F + t];
        #pragma unroll
        for (int i = 0; i < NPB; i++) {
            float4 xv = *(const float4*)&h1[i][k];
            acc[i] += xv.x*w0 + xv.y*w1 + xv.z*w2 + xv.w*w3;
        }
    }
    #pragma unroll
    for (int i = 0; i < NPB; i++) {
        size_t base = ((size_t)b * NN_ + n0 + i);
        out_h[base * F + t] = zs[i][t] + acc[i];
    }
}

// ---------------- coord kernels ----------------
__global__ void coord_kernel_csr(
    const float* __restrict__ coord, const float* __restrict__ trans_g,
    const int* __restrict__ bucket, const int* __restrict__ csr_off,
    float* __restrict__ out_c)
{
    const int t = threadIdx.x;
    const int lane = t & 63, wv = t >> 6;
    int nl = blockIdx.x * 4 + wv;          // 0..9999
    int b = nl / NN_, n = nl - b * NN_;
    int o0 = csr_off[n], o1 = csr_off[n + 1];
    if (lane < 12) {
        float s = 0.f;
        for (int k = o0; k < o1; k++) {
            int e = bucket[k];
            s += trans_g[((size_t)b * NE_ + e) * 12 + lane];
        }
        size_t ci = ((size_t)b * NN_ + n) * 12 + lane;
        out_c[ci] = coord[ci] + s / fmaxf((float)(o1 - o0), 1.0f);
    }
}

__global__ void coord_kernel_fb(
    const float* __restrict__ coord, const float* __restrict__ agg_c,
    const float* __restrict__ cnt, float* __restrict__ out_c)
{
    int i = blockIdx.x * 256 + threadIdx.x;
    if (i < B * NN_ * 12) {
        int node = i / 12;
        out_c[i] = coord[i] + agg_c[i] / fmaxf(cnt[node], 1.0f);
    }
}

extern "C" void kernel_launch(void* const* d_in, const int* in_sizes, int n_in,
                              void* d_out, int out_size, void* d_ws, size_t ws_size,
                              hipStream_t stream) {
    const float* h     = (const float*)d_in[0];
    const float* coord = (const float*)d_in[1];
    const int*   ei    = (const int*)d_in[2];
    const float* ea    = (const float*)d_in[3];
    const float* We1   = (const float*)d_in[4];
    const float* be1   = (const float*)d_in[5];
    const float* We2   = (const float*)d_in[6];
    const float* be2   = (const float*)d_in[7];
    const float* Wn1   = (const float*)d_in[8];
    const float* bn1   = (const float*)d_in[9];
    const float* Wn2   = (const float*)d_in[10];
    const float* bn2   = (const float*)d_in[11];
    const float* Wc1   = (const float*)d_in[12];
    const float* bc1   = (const float*)d_in[13];
    const float* Wc2   = (const float*)d_in[14];

    float* out_h = (float*)d_out;                       // [B,N,F]
    float* out_c = out_h + (size_t)B * NN_ * F;         // [B,N,4,3]

    unsigned char* base = (unsigned char*)d_ws;
    __bf16* pw1  = (__bf16*)base;             // 36864 bf16
    __bf16* pw2  = pw1 + 36864;               // 16384
    __bf16* pwc1 = pw2 + 16384;               // 16384
    __bf16* pwc2 = pwc1 + 16384;              // 2048  -> 143360 B total
    unsigned char* dyn = base + 143360;

    const size_t need_csr = 143360UL + 20000 + 20016 + 20000 + 640000
                          + 81920000UL + 15360000UL;    // 98,123,376
    bool use_csr = (ws_size >= need_csr);

    pack_weights<<<280, 256, 0, stream>>>(We1, We2, Wc1, Wc2, pw1, pw2, pwc1, pwc2);

    if (use_csr) {
        int* csr_cnt = (int*)(dyn);
        int* csr_off = (int*)(dyn + 20000);
        int* csr_pos = (int*)(dyn + 40016);
        int* bucket  = (int*)(dyn + 60016);
        unsigned* ef_g = (unsigned*)(dyn + 700016);         // [B][E][128] bf16 as dwords
        float* trans_g = (float*)(dyn + 82620016UL);        // [B][E][12] fp32

        hipMemsetAsync(csr_cnt, 0, 20000, stream);
        hist_kernel<<<625, 256, 0, stream>>>(ei, csr_cnt);
        scan_kernel<<<1, 256, 0, stream>>>(csr_cnt, csr_off, csr_pos);
        bucket_kernel<<<625, 256, 0, stream>>>(ei, csr_pos, bucket);

        dim3 eg(NE_ / 64, B);   // 2500 x 2
        edge_kernel<true><<<eg, 256, 0, stream>>>(h, coord, ei, ea, be1, be2, bc1,
                                                  pw1, pw2, pwc1, pwc2,
                                                  nullptr, nullptr, nullptr, ef_g, trans_g);
        dim3 ng(NN_ / NPB, B);  // 625 x 2
        node_kernel_csr<<<ng, 128, 0, stream>>>(h, (const unsigned short*)ef_g, bucket, csr_off,
                                                Wn1, bn1, Wn2, bn2, out_h);
        coord_kernel_csr<<<(B * NN_) / 4, 256, 0, stream>>>(coord, trans_g, bucket, csr_off, out_c);
    } else {
        float* agg_h = (float*)dyn;                          // [B,N,HID]
        float* agg_c = agg_h + (size_t)B * NN_ * HID;        // [B,N,12]
        float* cnt   = agg_c + (size_t)B * NN_ * 12;         // [B,N]

        size_t zero_bytes = ((size_t)B * NN_ * (HID + 12 + 1)) * sizeof(float);
        hipMemsetAsync(dyn, 0, zero_bytes, stream);

        dim3 eg(NE_ / 64, B);
        edge_kernel<false><<<eg, 256, 0, stream>>>(h, coord, ei, ea, be1, be2, bc1,
                                                   pw1, pw2, pwc1, pwc2,
                                                   agg_h, agg_c, cnt, nullptr, nullptr);
        dim3 ng(NN_ / NPB, B);
        node_kernel_fb<<<ng, 128, 0, stream>>>(h, agg_h, Wn1, bn1, Wn2, bn2, out_h);
        int cn = (B * NN_ * 12 + 255) / 256;
        coord_kernel_fb<<<cn, 256, 0, stream>>>(coord, agg_c, cnt, out_c);
    }
}

// Round 4
// 306.205 us; speedup vs baseline: 1.3783x; 1.3783x over previous
//
#include <hip/hip_runtime.h>
#include <hip/hip_bf16.h>

#define B   2
#define NN_ 5000
#define NE_ 160000
#define F   128
#define HID 128
#define ED  16
#define IN_EDGE 288   // 2*F + 16 + ED

typedef __bf16 bf16x8 __attribute__((ext_vector_type(8)));
typedef __bf16 bf16x4 __attribute__((ext_vector_type(4)));
typedef float  f32x4  __attribute__((ext_vector_type(4)));

#define XSS 296   // xs row stride (bf16): 16B-aligned rows, 2-way banks (free)
#define MS  136   // mid-buffer row stride

// ---------------- weight pack: row-major fp32 [K][N] -> bf16 MFMA B-fragments ----
__global__ void pack_weights(const float* __restrict__ We1, const float* __restrict__ We2,
                             const float* __restrict__ Wc1, const float* __restrict__ Wc2,
                             __bf16* __restrict__ pw1, __bf16* __restrict__ pw2,
                             __bf16* __restrict__ pwc1, __bf16* __restrict__ pwc2)
{
    int idx = blockIdx.x * 256 + threadIdx.x;   // 0 .. 71679
    const float* W; __bf16* P; int KT, Nr, local;
    if (idx < 36864)      { W = We1; P = pw1;  KT = 9; Nr = 128; local = idx; }
    else if (idx < 53248) { W = We2; P = pw2;  KT = 4; Nr = 128; local = idx - 36864; }
    else if (idx < 69632) { W = Wc1; P = pwc1; KT = 4; Nr = 128; local = idx - 53248; }
    else                  { W = Wc2; P = pwc2; KT = 4; Nr = 4;   local = idx - 69632; }
    int j = local & 7, lane = (local >> 3) & 63, rest = local >> 9;
    int kt = rest % KT, nt = rest / KT;
    int k = kt * 32 + (lane >> 4) * 8 + j;
    int n = nt * 16 + (lane & 15);
    float v = (n < Nr) ? W[k * Nr + n] : 0.f;
    P[local] = (__bf16)v;
}

// ---------------- CSR build ----------------
__global__ void hist_kernel(const int* __restrict__ ei, int* __restrict__ csr_cnt)
{
    int i = blockIdx.x * 256 + threadIdx.x;
    if (i < NE_) atomicAdd(&csr_cnt[ei[i]], 1);
}

__global__ void scan_kernel(const int* __restrict__ csr_cnt,
                            int* __restrict__ csr_off, int* __restrict__ csr_pos)
{
    __shared__ int part[256];
    const int t = threadIdx.x;
    int sum = 0;
    #pragma unroll
    for (int j = 0; j < 20; j++) {
        int idx = t * 20 + j;
        if (idx < NN_) sum += csr_cnt[idx];
    }
    part[t] = sum;
    __syncthreads();
    if (t == 0) {
        int run = 0;
        for (int i = 0; i < 256; i++) { int v = part[i]; part[i] = run; run += v; }
    }
    __syncthreads();
    int run = part[t];
    #pragma unroll
    for (int j = 0; j < 20; j++) {
        int idx = t * 20 + j;
        if (idx < NN_) { csr_off[idx] = run; csr_pos[idx] = run; run += csr_cnt[idx]; }
    }
    if (t == 0) csr_off[NN_] = NE_;
}

__global__ void bucket_kernel(const int* __restrict__ ei,
                              int* __restrict__ csr_pos, int* __restrict__ bucket)
{
    int i = blockIdx.x * 256 + threadIdx.x;
    if (i < NE_) { int p = atomicAdd(&csr_pos[ei[i]], 1); bucket[p] = i; }
}

// ------- edge kernel: sorted gather -> 4-layer MFMA MLP -> segmented reduce ----
__global__ __launch_bounds__(256) void edge_kernel(
    const float* __restrict__ h, const float* __restrict__ coord,
    const int* __restrict__ ei, const float* __restrict__ ea,
    const int* __restrict__ bucket,
    const float* __restrict__ be1, const float* __restrict__ be2,
    const float* __restrict__ bc1,
    const __bf16* __restrict__ pw1, const __bf16* __restrict__ pw2,
    const __bf16* __restrict__ pwc1, const __bf16* __restrict__ pwc2,
    float* __restrict__ agg_h, float* __restrict__ agg_c)
{
    __shared__ __align__(16) __bf16 R[18944];        // xs[64][296] | buf1/buf2[64][136]
    __shared__ float cds[64][12];
    __shared__ int rs[64], cs[64];

    const int t = threadIdx.x;
    const int b = blockIdx.y;
    const int p0 = blockIdx.x * 64;                  // sorted edge-slot base
    const int lane = t & 63, wave = t >> 6;
    const int quad = lane >> 4, c = lane & 15;

    if (t < 64) {
        int eid = bucket[p0 + t];
        rs[t] = ei[eid]; cs[t] = ei[NE_ + eid];
    }
    __syncthreads();

    // ---- stage xs = [h_row | h_col | radial | edge_attr] as bf16 ----
    const float* hb = h + (size_t)b * NN_ * F;
    #pragma unroll
    for (int eb = 0; eb < 64; eb += 4) {
        int e = eb + wave;
        int node, dst;
        if (lane < 32) { node = rs[e]; dst = lane * 4; }   // row: L1-hot (sorted)
        else           { node = cs[e]; dst = F + (lane - 32) * 4; }
        float4 v = *(const float4*)(hb + (size_t)node * F + (lane & 31) * 4);
        bf16x4 bv = { (__bf16)v.x, (__bf16)v.y, (__bf16)v.z, (__bf16)v.w };
        *(bf16x4*)&R[e * XSS + dst] = bv;
    }
    if (t < 64) {
        int e = t;
        int eid = bucket[p0 + t];
        const float* cr = coord + ((size_t)b * NN_ + rs[e]) * 12;
        const float* cc = coord + ((size_t)b * NN_ + cs[e]) * 12;
        float cd[12];
        #pragma unroll
        for (int j = 0; j < 12; j++) { cd[j] = cr[j] - cc[j]; cds[e][j] = cd[j]; }
        float prod[16]; float ss = 0.f;
        #pragma unroll
        for (int j = 0; j < 4; j++)
            #pragma unroll
            for (int k = 0; k < 4; k++) {
                float p = cd[j*3]*cd[k*3] + cd[j*3+1]*cd[k*3+1] + cd[j*3+2]*cd[k*3+2];
                prod[j*4 + k] = p; ss += p * p;
            }
        float inv = 1.0f / fmaxf(sqrtf(ss), 1e-12f);
        #pragma unroll
        for (int j = 0; j < 16; j++) R[e * XSS + 2*F + j] = (__bf16)(prod[j] * inv);
        const float* eap = ea + (size_t)eid * ED;
        #pragma unroll
        for (int j = 0; j < 4; j++) {
            float4 v = *(const float4*)(eap + j * 4);
            bf16x4 bv = { (__bf16)v.x, (__bf16)v.y, (__bf16)v.z, (__bf16)v.w };
            *(bf16x4*)&R[e * XSS + 2*F + 16 + j*4] = bv;
        }
    }
    __syncthreads();

    const bf16x8* pw1v  = (const bf16x8*)pw1;
    const bf16x8* pw2v  = (const bf16x8*)pw2;
    const bf16x8* pwc1v = (const bf16x8*)pwc1;
    const bf16x8* pwc2v = (const bf16x8*)pwc2;
    __bf16* buf1 = R;
    __bf16* buf2 = R + 8704;   // 64*136

    // ---- layer e1: x(288) @ We1 ----
    f32x4 acc[8];
    #pragma unroll
    for (int nt = 0; nt < 8; nt++) acc[nt] = (f32x4){0.f, 0.f, 0.f, 0.f};
    for (int kt = 0; kt < 9; kt++) {
        bf16x8 a = *(const bf16x8*)&R[(wave*16 + c) * XSS + kt*32 + quad*8];
        #pragma unroll
        for (int nt = 0; nt < 8; nt++)
            acc[nt] = __builtin_amdgcn_mfma_f32_16x16x32_bf16(a, pw1v[(nt*9 + kt)*64 + lane], acc[nt], 0, 0, 0);
    }
    __syncthreads();   // xs dead; R reusable
    #pragma unroll
    for (int nt = 0; nt < 8; nt++)
        #pragma unroll
        for (int i = 0; i < 4; i++) {
            float v = fmaxf(acc[nt][i] + be1[nt*16 + c], 0.f);
            buf1[(wave*16 + quad*4 + i) * MS + nt*16 + c] = (__bf16)v;
        }
    __syncthreads();

    // ---- layer e2: h1 @ We2 -> ef (stays in buf2 for the reduction) ----
    f32x4 acc2[8];
    #pragma unroll
    for (int nt = 0; nt < 8; nt++) acc2[nt] = (f32x4){0.f, 0.f, 0.f, 0.f};
    for (int kt = 0; kt < 4; kt++) {
        bf16x8 a = *(const bf16x8*)&buf1[(wave*16 + c) * MS + kt*32 + quad*8];
        #pragma unroll
        for (int nt = 0; nt < 8; nt++)
            acc2[nt] = __builtin_amdgcn_mfma_f32_16x16x32_bf16(a, pw2v[(nt*4 + kt)*64 + lane], acc2[nt], 0, 0, 0);
    }
    #pragma unroll
    for (int nt = 0; nt < 8; nt++)
        #pragma unroll
        for (int i = 0; i < 4; i++) {
            float v = fmaxf(acc2[nt][i] + be2[nt*16 + c], 0.f);
            buf2[(wave*16 + quad*4 + i) * MS + nt*16 + c] = (__bf16)v;
        }
    __syncthreads();

    // ---- coord layer c1: ef @ Wc1 ----
    f32x4 acc3[8];
    #pragma unroll
    for (int nt = 0; nt < 8; nt++) acc3[nt] = (f32x4){0.f, 0.f, 0.f, 0.f};
    for (int kt = 0; kt < 4; kt++) {
        bf16x8 a = *(const bf16x8*)&buf2[(wave*16 + c) * MS + kt*32 + quad*8];
        #pragma unroll
        for (int nt = 0; nt < 8; nt++)
            acc3[nt] = __builtin_amdgcn_mfma_f32_16x16x32_bf16(a, pwc1v[(nt*4 + kt)*64 + lane], acc3[nt], 0, 0, 0);
    }
    __syncthreads();
    #pragma unroll
    for (int nt = 0; nt < 8; nt++)
        #pragma unroll
        for (int i = 0; i < 4; i++) {
            float v = fmaxf(acc3[nt][i] + bc1[nt*16 + c], 0.f);
            buf1[(wave*16 + quad*4 + i) * MS + nt*16 + c] = (__bf16)v;
        }
    __syncthreads();

    // ---- coord layer c2: h2 @ Wc2 (128x4 zero-padded to 16 cols) ----
    f32x4 accw = (f32x4){0.f, 0.f, 0.f, 0.f};
    for (int kt = 0; kt < 4; kt++) {
        bf16x8 a = *(const bf16x8*)&buf1[(wave*16 + c) * MS + kt*32 + quad*8];
        accw = __builtin_amdgcn_mfma_f32_16x16x32_bf16(a, pwc2v[kt*64 + lane], accw, 0, 0, 0);
    }
    // trans = cd * w, in place in cds
    if (c < 4) {
        #pragma unroll
        for (int i = 0; i < 4; i++) {
            int el = wave*16 + quad*4 + i;
            float w = accw[i];
            #pragma unroll
            for (int d = 0; d < 3; d++) cds[el][c*3 + d] *= w;
        }
    }
    __syncthreads();

    // ---- segmented reduction over sorted rows -> few atomics ----
    // agg_h: 2 threads/col, each scans 32 edges. Flush branch is wave-uniform
    // (waves 0,1 -> edges 0..31; waves 2,3 -> edges 32..63).
    {
        float* aggh_b = agg_h + (size_t)b * NN_ * HID;
        const int col = t & 127, half = t >> 7;
        float run = 0.f;
        int cur = rs[half * 32];
        for (int e = half * 32; e < half * 32 + 32; e++) {
            int r = rs[e];
            float v = (float)buf2[e * MS + col];
            if (r != cur) {
                atomicAdd(&aggh_b[(size_t)cur * HID + col], run);
                run = 0.f; cur = r;
            }
            run += v;
        }
        atomicAdd(&aggh_b[(size_t)cur * HID + col], run);
    }
    // agg_c: 12 cols x 4 quarters of 16 edges
    if (t < 48) {
        float* aggc_b = agg_c + (size_t)b * NN_ * 12;
        const int j = t % 12, q = t / 12;
        float run = 0.f;
        int cur = rs[q * 16];
        for (int e = q * 16; e < q * 16 + 16; e++) {
            int r = rs[e];
            float v = cds[e][j];
            if (r != cur) {
                atomicAdd(&aggc_b[(size_t)cur * 12 + j], run);
                run = 0.f; cur = r;
            }
            run += v;
        }
        atomicAdd(&aggc_b[(size_t)cur * 12 + j], run);
    }
}

// ---------------- node kernel (reads precomputed agg_h) ----------------
#define NPB 8
__global__ __launch_bounds__(128) void node_kernel(
    const float* __restrict__ h, const float* __restrict__ agg_h,
    const float* __restrict__ Wn1, const float* __restrict__ bn1,
    const float* __restrict__ Wn2, const float* __restrict__ bn2,
    float* __restrict__ out_h)
{
    __shared__ float zs[NPB][2 * F];
    __shared__ float h1[NPB][HID];
    const int t  = threadIdx.x;
    const int b  = blockIdx.y;
    const int n0 = blockIdx.x * NPB;

    #pragma unroll
    for (int i = 0; i < NPB; i++) {
        size_t base = ((size_t)b * NN_ + n0 + i);
        zs[i][t]     = h[base * F + t];
        zs[i][F + t] = agg_h[base * HID + t];
    }
    __syncthreads();

    float acc[NPB];
    #pragma unroll
    for (int i = 0; i < NPB; i++) acc[i] = bn1[t];
    for (int k = 0; k < 2 * F; k += 4) {
        float w0 = Wn1[(k+0)*HID + t], w1 = Wn1[(k+1)*HID + t];
        float w2 = Wn1[(k+2)*HID + t], w3 = Wn1[(k+3)*HID + t];
        #pragma unroll
        for (int i = 0; i < NPB; i++) {
            float4 xv = *(const float4*)&zs[i][k];
            acc[i] += xv.x*w0 + xv.y*w1 + xv.z*w2 + xv.w*w3;
        }
    }
    __syncthreads();
    #pragma unroll
    for (int i = 0; i < NPB; i++) h1[i][t] = fmaxf(acc[i], 0.f);
    __syncthreads();

    #pragma unroll
    for (int i = 0; i < NPB; i++) acc[i] = bn2[t];
    for (int k = 0; k < HID; k += 4) {
        float w0 = Wn2[(k+0)*F + t], w1 = Wn2[(k+1)*F + t];
        float w2 = Wn2[(k+2)*F + t], w3 = Wn2[(k+3)*F + t];
        #pragma unroll
        for (int i = 0; i < NPB; i++) {
            float4 xv = *(const float4*)&h1[i][k];
            acc[i] += xv.x*w0 + xv.y*w1 + xv.z*w2 + xv.w*w3;
        }
    }
    #pragma unroll
    for (int i = 0; i < NPB; i++) {
        size_t base = ((size_t)b * NN_ + n0 + i);
        out_h[base * F + t] = zs[i][t] + acc[i];
    }
}

// ---------------- coord kernel (degree from csr_off) ----------------
__global__ void coord_kernel(
    const float* __restrict__ coord, const float* __restrict__ agg_c,
    const int* __restrict__ csr_off, float* __restrict__ out_c)
{
    int i = blockIdx.x * 256 + threadIdx.x;
    if (i < B * NN_ * 12) {
        int node = i / 12;
        int n = node % NN_;
        float deg = (float)(csr_off[n + 1] - csr_off[n]);
        out_c[i] = coord[i] + agg_c[i] / fmaxf(deg, 1.0f);
    }
}

extern "C" void kernel_launch(void* const* d_in, const int* in_sizes, int n_in,
                              void* d_out, int out_size, void* d_ws, size_t ws_size,
                              hipStream_t stream) {
    const float* h     = (const float*)d_in[0];
    const float* coord = (const float*)d_in[1];
    const int*   ei    = (const int*)d_in[2];
    const float* ea    = (const float*)d_in[3];
    const float* We1   = (const float*)d_in[4];
    const float* be1   = (const float*)d_in[5];
    const float* We2   = (const float*)d_in[6];
    const float* be2   = (const float*)d_in[7];
    const float* Wn1   = (const float*)d_in[8];
    const float* bn1   = (const float*)d_in[9];
    const float* Wn2   = (const float*)d_in[10];
    const float* bn2   = (const float*)d_in[11];
    const float* Wc1   = (const float*)d_in[12];
    const float* bc1   = (const float*)d_in[13];
    const float* Wc2   = (const float*)d_in[14];

    float* out_h = (float*)d_out;                       // [B,N,F]
    float* out_c = out_h + (size_t)B * NN_ * F;         // [B,N,4,3]

    unsigned char* base = (unsigned char*)d_ws;
    __bf16* pw1  = (__bf16*)base;             // 36864 bf16
    __bf16* pw2  = pw1 + 36864;               // 16384
    __bf16* pwc1 = pw2 + 16384;               // 16384
    __bf16* pwc2 = pwc1 + 16384;              // 2048  -> 143360 B total
    unsigned char* dyn = base + 143360;

    int* csr_cnt = (int*)(dyn);               // 20000 B
    int* csr_off = (int*)(dyn + 20000);       // 20016 B (5001 ints, padded)
    int* csr_pos = (int*)(dyn + 40016);       // 20000 B
    int* bucket  = (int*)(dyn + 60016);       // 640000 B
    float* agg_h = (float*)(dyn + 700016);    // [B,N,HID]  5,120,000 B
    float* agg_c = agg_h + (size_t)B * NN_ * HID;   // [B,N,12]  480,000 B

    pack_weights<<<280, 256, 0, stream>>>(We1, We2, Wc1, Wc2, pw1, pw2, pwc1, pwc2);

    hipMemsetAsync(csr_cnt, 0, 20000, stream);
    hipMemsetAsync(agg_h, 0, (size_t)B * NN_ * (HID + 12) * sizeof(float), stream);

    hist_kernel<<<625, 256, 0, stream>>>(ei, csr_cnt);
    scan_kernel<<<1, 256, 0, stream>>>(csr_cnt, csr_off, csr_pos);
    bucket_kernel<<<625, 256, 0, stream>>>(ei, csr_pos, bucket);

    dim3 eg(NE_ / 64, B);   // 2500 x 2
    edge_kernel<<<eg, 256, 0, stream>>>(h, coord, ei, ea, bucket, be1, be2, bc1,
                                        pw1, pw2, pwc1, pwc2, agg_h, agg_c);

    dim3 ng(NN_ / NPB, B);  // 625 x 2
    node_kernel<<<ng, 128, 0, stream>>>(h, agg_h, Wn1, bn1, Wn2, bn2, out_h);

    int cn = (B * NN_ * 12 + 255) / 256;
    coord_kernel<<<cn, 256, 0, stream>>>(coord, agg_c, csr_off, out_c);
}

// Round 5
// 273.496 us; speedup vs baseline: 1.5432x; 1.1196x over previous
//
#include <hip/hip_runtime.h>
#include <hip/hip_bf16.h>

#define B   2
#define NN_ 5000
#define NE_ 160000
#define F   128
#define HID 128
#define ED  16
#define IN_EDGE 288   // 2*F + 16 + ED

typedef __bf16 bf16x8 __attribute__((ext_vector_type(8)));
typedef __bf16 bf16x4 __attribute__((ext_vector_type(4)));
typedef float  f32x4  __attribute__((ext_vector_type(4)));

#define XSS 296   // xs row stride (bf16): 16B-aligned rows
#define MS  136   // mid-buffer row stride

// ---------------- weight pack: row-major fp32 [K][N] -> bf16 MFMA B-fragments ----
__global__ void pack_weights(const float* __restrict__ We1, const float* __restrict__ We2,
                             const float* __restrict__ Wc1, const float* __restrict__ Wc2,
                             __bf16* __restrict__ pw1, __bf16* __restrict__ pw2,
                             __bf16* __restrict__ pwc1, __bf16* __restrict__ pwc2)
{
    int idx = blockIdx.x * 256 + threadIdx.x;   // 0 .. 71679
    const float* W; __bf16* P; int KT, Nr, local;
    if (idx < 36864)      { W = We1; P = pw1;  KT = 9; Nr = 128; local = idx; }
    else if (idx < 53248) { W = We2; P = pw2;  KT = 4; Nr = 128; local = idx - 36864; }
    else if (idx < 69632) { W = Wc1; P = pwc1; KT = 4; Nr = 128; local = idx - 53248; }
    else                  { W = Wc2; P = pwc2; KT = 4; Nr = 4;   local = idx - 69632; }
    int j = local & 7, lane = (local >> 3) & 63, rest = local >> 9;
    int kt = rest % KT, nt = rest / KT;
    int k = kt * 32 + (lane >> 4) * 8 + j;
    int n = nt * 16 + (lane & 15);
    float v = (n < Nr) ? W[k * Nr + n] : 0.f;
    P[local] = (__bf16)v;
}

// ---------------- CSR build ----------------
__global__ void hist_kernel(const int* __restrict__ ei, int* __restrict__ csr_cnt)
{
    int i = blockIdx.x * 256 + threadIdx.x;
    if (i < NE_) atomicAdd(&csr_cnt[ei[i]], 1);
}

__global__ void scan_kernel(const int* __restrict__ csr_cnt,
                            int* __restrict__ csr_off, int* __restrict__ csr_pos)
{
    __shared__ int part[256];
    const int t = threadIdx.x;
    int sum = 0;
    #pragma unroll
    for (int j = 0; j < 20; j++) {
        int idx = t * 20 + j;
        if (idx < NN_) sum += csr_cnt[idx];
    }
    part[t] = sum;
    __syncthreads();
    if (t == 0) {
        int run = 0;
        for (int i = 0; i < 256; i++) { int v = part[i]; part[i] = run; run += v; }
    }
    __syncthreads();
    int run = part[t];
    #pragma unroll
    for (int j = 0; j < 20; j++) {
        int idx = t * 20 + j;
        if (idx < NN_) { csr_off[idx] = run; csr_pos[idx] = run; run += csr_cnt[idx]; }
    }
    if (t == 0) csr_off[NN_] = NE_;
}

__global__ void bucket_kernel(const int* __restrict__ ei,
                              int* __restrict__ csr_pos, int* __restrict__ bucket)
{
    int i = blockIdx.x * 256 + threadIdx.x;
    if (i < NE_) { int p = atomicAdd(&csr_pos[ei[i]], 1); bucket[p] = i; }
}

// ---------------- h -> bf16 ----------------
__global__ void h2b_kernel(const float* __restrict__ h, __bf16* __restrict__ hb16)
{
    int i = blockIdx.x * 256 + threadIdx.x;   // float4 index, 320000 total
    if (i < B * NN_ * F / 4) {
        float4 v = ((const float4*)h)[i];
        bf16x4 bv = {(__bf16)v.x, (__bf16)v.y, (__bf16)v.z, (__bf16)v.w};
        ((bf16x4*)hb16)[i] = bv;
    }
}

// ---------------- edge_attr -> bf16, permuted into sorted (bucket) order -------
__global__ void ea_sort_kernel(const float* __restrict__ ea, const int* __restrict__ bucket,
                               __bf16* __restrict__ eas)
{
    int idx = blockIdx.x * 256 + threadIdx.x;  // 640000
    if (idx < NE_ * 4) {
        int p = idx >> 2, j = idx & 3;
        int e = bucket[p];
        float4 v = ((const float4*)ea)[e * 4 + j];
        bf16x4 bv = {(__bf16)v.x, (__bf16)v.y, (__bf16)v.z, (__bf16)v.w};
        *(bf16x4*)&eas[p * 16 + j * 4] = bv;
    }
}

// ------- edge kernel: sorted gather -> 4-layer MFMA MLP (N-split) -> seg-reduce ----
__global__ __launch_bounds__(256) void edge_kernel(
    const __bf16* __restrict__ hb16, const float* __restrict__ coord,
    const int* __restrict__ ei, const __bf16* __restrict__ eas,
    const int* __restrict__ bucket,
    const float* __restrict__ be1, const float* __restrict__ be2,
    const float* __restrict__ bc1,
    const __bf16* __restrict__ pw1, const __bf16* __restrict__ pw2,
    const __bf16* __restrict__ pwc1, const __bf16* __restrict__ pwc2,
    float* __restrict__ agg_h, float* __restrict__ agg_c)
{
    __shared__ __align__(16) __bf16 R[18944];        // xs[64][296] | buf1/buf2[64][136]
    __shared__ float cds[64][12];
    __shared__ int rs[64], cs[64];

    const int t = threadIdx.x;
    const int b = blockIdx.y;
    const int p0 = blockIdx.x * 64;                  // sorted edge-slot base
    const int lane = t & 63, wave = t >> 6;
    const int quad = lane >> 4, c = lane & 15;

    if (t < 64) {
        int eid = bucket[p0 + t];
        rs[t] = ei[eid]; cs[t] = ei[NE_ + eid];
    }
    __syncthreads();

    // ---- stage xs = [h_row | h_col] as 16B copies from bf16 h ----
    const __bf16* hb = hb16 + (size_t)b * NN_ * F;
    #pragma unroll
    for (int i = 0; i < 8; i++) {
        int e = i * 8 + (t >> 5);
        int ch = t & 31;                              // 32 chunks of 16B per edge
        int node = (ch < 16) ? rs[e] : cs[e];
        uint4 v = *(const uint4*)(hb + (size_t)node * F + (ch & 15) * 8);
        *(uint4*)&R[e * XSS + ch * 8] = v;
    }
    // ---- radial + ea (one thread per edge) ----
    if (t < 64) {
        int e = t;
        const float* cr = coord + ((size_t)b * NN_ + rs[e]) * 12;
        const float* cc = coord + ((size_t)b * NN_ + cs[e]) * 12;
        float cd[12];
        #pragma unroll
        for (int j = 0; j < 12; j++) { cd[j] = cr[j] - cc[j]; cds[e][j] = cd[j]; }
        float prod[16]; float ss = 0.f;
        #pragma unroll
        for (int j = 0; j < 4; j++)
            #pragma unroll
            for (int k = 0; k < 4; k++) {
                float p = cd[j*3]*cd[k*3] + cd[j*3+1]*cd[k*3+1] + cd[j*3+2]*cd[k*3+2];
                prod[j*4 + k] = p; ss += p * p;
            }
        float inv = 1.0f / fmaxf(sqrtf(ss), 1e-12f);
        #pragma unroll
        for (int j = 0; j < 16; j++) R[e * XSS + 2*F + j] = (__bf16)(prod[j] * inv);
        const uint4* ep = (const uint4*)(eas + (size_t)(p0 + e) * 16);
        *(uint4*)&R[e * XSS + 2*F + 16] = ep[0];
        *(uint4*)&R[e * XSS + 2*F + 24] = ep[1];
    }
    __syncthreads();

    const bf16x8* pw1v  = (const bf16x8*)pw1;
    const bf16x8* pw2v  = (const bf16x8*)pw2;
    const bf16x8* pwc1v = (const bf16x8*)pwc1;
    const bf16x8* pwc2v = (const bf16x8*)pwc2;
    __bf16* buf1 = R;
    __bf16* buf2 = R + 8704;   // 64*136

    // ---- layer e1: x(288) @ We1 — N-split: wave handles nt = 2*wave..2*wave+1,
    //      all 4 M-tiles (64 edges). Each weight frag loaded ONCE per block. ----
    f32x4 acc1[4][2];
    #pragma unroll
    for (int m = 0; m < 4; m++)
        #pragma unroll
        for (int n = 0; n < 2; n++) acc1[m][n] = (f32x4){0.f, 0.f, 0.f, 0.f};
    for (int kt = 0; kt < 9; kt++) {
        bf16x8 a[4];
        #pragma unroll
        for (int m = 0; m < 4; m++)
            a[m] = *(const bf16x8*)&R[(m*16 + c) * XSS + kt*32 + quad*8];
        #pragma unroll
        for (int n = 0; n < 2; n++) {
            bf16x8 w = pw1v[((2*wave + n)*9 + kt)*64 + lane];
            #pragma unroll
            for (int m = 0; m < 4; m++)
                acc1[m][n] = __builtin_amdgcn_mfma_f32_16x16x32_bf16(a[m], w, acc1[m][n], 0, 0, 0);
        }
    }
    __syncthreads();   // all xs reads done; R reusable
    #pragma unroll
    for (int n = 0; n < 2; n++) {
        float bias = be1[(2*wave + n)*16 + c];
        #pragma unroll
        for (int m = 0; m < 4; m++)
            #pragma unroll
            for (int i = 0; i < 4; i++) {
                float v = fmaxf(acc1[m][n][i] + bias, 0.f);
                buf1[(m*16 + quad*4 + i) * MS + (2*wave + n)*16 + c] = (__bf16)v;
            }
    }
    __syncthreads();

    // ---- layer e2: h1 @ We2 -> ef ----
    f32x4 acc2[4][2];
    #pragma unroll
    for (int m = 0; m < 4; m++)
        #pragma unroll
        for (int n = 0; n < 2; n++) acc2[m][n] = (f32x4){0.f, 0.f, 0.f, 0.f};
    for (int kt = 0; kt < 4; kt++) {
        bf16x8 a[4];
        #pragma unroll
        for (int m = 0; m < 4; m++)
            a[m] = *(const bf16x8*)&buf1[(m*16 + c) * MS + kt*32 + quad*8];
        #pragma unroll
        for (int n = 0; n < 2; n++) {
            bf16x8 w = pw2v[((2*wave + n)*4 + kt)*64 + lane];
            #pragma unroll
            for (int m = 0; m < 4; m++)
                acc2[m][n] = __builtin_amdgcn_mfma_f32_16x16x32_bf16(a[m], w, acc2[m][n], 0, 0, 0);
        }
    }
    #pragma unroll
    for (int n = 0; n < 2; n++) {
        float bias = be2[(2*wave + n)*16 + c];
        #pragma unroll
        for (int m = 0; m < 4; m++)
            #pragma unroll
            for (int i = 0; i < 4; i++) {
                float v = fmaxf(acc2[m][n][i] + bias, 0.f);
                buf2[(m*16 + quad*4 + i) * MS + (2*wave + n)*16 + c] = (__bf16)v;
            }
    }
    __syncthreads();

    // ---- coord layer c1: ef @ Wc1 ----
    f32x4 acc3[4][2];
    #pragma unroll
    for (int m = 0; m < 4; m++)
        #pragma unroll
        for (int n = 0; n < 2; n++) acc3[m][n] = (f32x4){0.f, 0.f, 0.f, 0.f};
    for (int kt = 0; kt < 4; kt++) {
        bf16x8 a[4];
        #pragma unroll
        for (int m = 0; m < 4; m++)
            a[m] = *(const bf16x8*)&buf2[(m*16 + c) * MS + kt*32 + quad*8];
        #pragma unroll
        for (int n = 0; n < 2; n++) {
            bf16x8 w = pwc1v[((2*wave + n)*4 + kt)*64 + lane];
            #pragma unroll
            for (int m = 0; m < 4; m++)
                acc3[m][n] = __builtin_amdgcn_mfma_f32_16x16x32_bf16(a[m], w, acc3[m][n], 0, 0, 0);
        }
    }
    #pragma unroll
    for (int n = 0; n < 2; n++) {
        float bias = bc1[(2*wave + n)*16 + c];
        #pragma unroll
        for (int m = 0; m < 4; m++)
            #pragma unroll
            for (int i = 0; i < 4; i++) {
                float v = fmaxf(acc3[m][n][i] + bias, 0.f);
                buf1[(m*16 + quad*4 + i) * MS + (2*wave + n)*16 + c] = (__bf16)v;
            }
    }
    __syncthreads();

    // ---- coord layer c2: h2 @ Wc2 (128x4 zero-padded; M-split, tiny weights) ----
    f32x4 accw = (f32x4){0.f, 0.f, 0.f, 0.f};
    for (int kt = 0; kt < 4; kt++) {
        bf16x8 a = *(const bf16x8*)&buf1[(wave*16 + c) * MS + kt*32 + quad*8];
        accw = __builtin_amdgcn_mfma_f32_16x16x32_bf16(a, pwc2v[kt*64 + lane], accw, 0, 0, 0);
    }
    // trans = cd * w, in place in cds
    if (c < 4) {
        #pragma unroll
        for (int i = 0; i < 4; i++) {
            int el = wave*16 + quad*4 + i;
            float w = accw[i];
            #pragma unroll
            for (int d = 0; d < 3; d++) cds[el][c*3 + d] *= w;
        }
    }
    __syncthreads();

    // ---- segmented reduction over sorted rows -> few atomics ----
    {
        float* aggh_b = agg_h + (size_t)b * NN_ * HID;
        const int col = t & 127, half = t >> 7;
        float run = 0.f;
        int cur = rs[half * 32];
        for (int e = half * 32; e < half * 32 + 32; e++) {
            int r = rs[e];
            float v = (float)buf2[e * MS + col];
            if (r != cur) {
                atomicAdd(&aggh_b[(size_t)cur * HID + col], run);
                run = 0.f; cur = r;
            }
            run += v;
        }
        atomicAdd(&aggh_b[(size_t)cur * HID + col], run);
    }
    if (t < 48) {
        float* aggc_b = agg_c + (size_t)b * NN_ * 12;
        const int j = t % 12, q = t / 12;
        float run = 0.f;
        int cur = rs[q * 16];
        for (int e = q * 16; e < q * 16 + 16; e++) {
            int r = rs[e];
            float v = cds[e][j];
            if (r != cur) {
                atomicAdd(&aggc_b[(size_t)cur * 12 + j], run);
                run = 0.f; cur = r;
            }
            run += v;
        }
        atomicAdd(&aggc_b[(size_t)cur * 12 + j], run);
    }
}

// ---------------- node kernel (reads precomputed agg_h) ----------------
#define NPB 8
__global__ __launch_bounds__(128) void node_kernel(
    const float* __restrict__ h, const float* __restrict__ agg_h,
    const float* __restrict__ Wn1, const float* __restrict__ bn1,
    const float* __restrict__ Wn2, const float* __restrict__ bn2,
    float* __restrict__ out_h)
{
    __shared__ float zs[NPB][2 * F];
    __shared__ float h1[NPB][HID];
    const int t  = threadIdx.x;
    const int b  = blockIdx.y;
    const int n0 = blockIdx.x * NPB;

    #pragma unroll
    for (int i = 0; i < NPB; i++) {
        size_t base = ((size_t)b * NN_ + n0 + i);
        zs[i][t]     = h[base * F + t];
        zs[i][F + t] = agg_h[base * HID + t];
    }
    __syncthreads();

    float acc[NPB];
    #pragma unroll
    for (int i = 0; i < NPB; i++) acc[i] = bn1[t];
    for (int k = 0; k < 2 * F; k += 4) {
        float w0 = Wn1[(k+0)*HID + t], w1 = Wn1[(k+1)*HID + t];
        float w2 = Wn1[(k+2)*HID + t], w3 = Wn1[(k+3)*HID + t];
        #pragma unroll
        for (int i = 0; i < NPB; i++) {
            float4 xv = *(const float4*)&zs[i][k];
            acc[i] += xv.x*w0 + xv.y*w1 + xv.z*w2 + xv.w*w3;
        }
    }
    __syncthreads();
    #pragma unroll
    for (int i = 0; i < NPB; i++) h1[i][t] = fmaxf(acc[i], 0.f);
    __syncthreads();

    #pragma unroll
    for (int i = 0; i < NPB; i++) acc[i] = bn2[t];
    for (int k = 0; k < HID; k += 4) {
        float w0 = Wn2[(k+0)*F + t], w1 = Wn2[(k+1)*F + t];
        float w2 = Wn2[(k+2)*F + t], w3 = Wn2[(k+3)*F + t];
        #pragma unroll
        for (int i = 0; i < NPB; i++) {
            float4 xv = *(const float4*)&h1[i][k];
            acc[i] += xv.x*w0 + xv.y*w1 + xv.z*w2 + xv.w*w3;
        }
    }
    #pragma unroll
    for (int i = 0; i < NPB; i++) {
        size_t base = ((size_t)b * NN_ + n0 + i);
        out_h[base * F + t] = zs[i][t] + acc[i];
    }
}

// ---------------- coord kernel (degree from csr_off) ----------------
__global__ void coord_kernel(
    const float* __restrict__ coord, const float* __restrict__ agg_c,
    const int* __restrict__ csr_off, float* __restrict__ out_c)
{
    int i = blockIdx.x * 256 + threadIdx.x;
    if (i < B * NN_ * 12) {
        int node = i / 12;
        int n = node % NN_;
        float deg = (float)(csr_off[n + 1] - csr_off[n]);
        out_c[i] = coord[i] + agg_c[i] / fmaxf(deg, 1.0f);
    }
}

extern "C" void kernel_launch(void* const* d_in, const int* in_sizes, int n_in,
                              void* d_out, int out_size, void* d_ws, size_t ws_size,
                              hipStream_t stream) {
    const float* h     = (const float*)d_in[0];
    const float* coord = (const float*)d_in[1];
    const int*   ei    = (const int*)d_in[2];
    const float* ea    = (const float*)d_in[3];
    const float* We1   = (const float*)d_in[4];
    const float* be1   = (const float*)d_in[5];
    const float* We2   = (const float*)d_in[6];
    const float* be2   = (const float*)d_in[7];
    const float* Wn1   = (const float*)d_in[8];
    const float* bn1   = (const float*)d_in[9];
    const float* Wn2   = (const float*)d_in[10];
    const float* bn2   = (const float*)d_in[11];
    const float* Wc1   = (const float*)d_in[12];
    const float* bc1   = (const float*)d_in[13];
    const float* Wc2   = (const float*)d_in[14];

    float* out_h = (float*)d_out;                       // [B,N,F]
    float* out_c = out_h + (size_t)B * NN_ * F;         // [B,N,4,3]

    unsigned char* base = (unsigned char*)d_ws;
    __bf16* pw1  = (__bf16*)base;             // 36864 bf16
    __bf16* pw2  = pw1 + 36864;               // 16384
    __bf16* pwc1 = pw2 + 16384;               // 16384
    __bf16* pwc2 = pwc1 + 16384;              // 2048  -> 143360 B total
    unsigned char* dyn = base + 143360;

    int* csr_cnt = (int*)(dyn);               // 20000 B
    int* csr_off = (int*)(dyn + 20000);       // 20016 B
    int* csr_pos = (int*)(dyn + 40016);       // 20000 B
    int* bucket  = (int*)(dyn + 60016);       // 640000 B
    float* agg_h = (float*)(dyn + 700016);    // [B,N,HID]  5,120,000 B
    float* agg_c = agg_h + (size_t)B * NN_ * HID;      // [B,N,12] 480,000 B
    __bf16* hb16 = (__bf16*)(agg_c + (size_t)B * NN_ * 12);  // 2,560,000 B
    __bf16* eas  = hb16 + (size_t)B * NN_ * F;               // 5,120,000 B

    pack_weights<<<280, 256, 0, stream>>>(We1, We2, Wc1, Wc2, pw1, pw2, pwc1, pwc2);

    hipMemsetAsync(csr_cnt, 0, 20000, stream);
    hipMemsetAsync(agg_h, 0, (size_t)B * NN_ * (HID + 12) * sizeof(float), stream);

    hist_kernel<<<625, 256, 0, stream>>>(ei, csr_cnt);
    scan_kernel<<<1, 256, 0, stream>>>(csr_cnt, csr_off, csr_pos);
    bucket_kernel<<<625, 256, 0, stream>>>(ei, csr_pos, bucket);
    h2b_kernel<<<1250, 256, 0, stream>>>(h, hb16);
    ea_sort_kernel<<<2500, 256, 0, stream>>>(ea, bucket, eas);

    dim3 eg(NE_ / 64, B);   // 2500 x 2
    edge_kernel<<<eg, 256, 0, stream>>>(hb16, coord, ei, eas, bucket, be1, be2, bc1,
                                        pw1, pw2, pwc1, pwc2, agg_h, agg_c);

    dim3 ng(NN_ / NPB, B);  // 625 x 2
    node_kernel<<<ng, 128, 0, stream>>>(h, agg_h, Wn1, bn1, Wn2, bn2, out_h);

    int cn = (B * NN_ * 12 + 255) / 256;
    coord_kernel<<<cn, 256, 0, stream>>>(coord, agg_c, csr_off, out_c);
}

// Round 6
// 257.184 us; speedup vs baseline: 1.6410x; 1.0634x over previous
//
#include <hip/hip_runtime.h>
#include <hip/hip_bf16.h>

#define B   2
#define NN_ 5000
#define NE_ 160000
#define F   128
#define HID 128
#define ED  16
#define IN_EDGE 288   // 2*F + 16 + ED

typedef __bf16 bf16x8 __attribute__((ext_vector_type(8)));
typedef __bf16 bf16x4 __attribute__((ext_vector_type(4)));
typedef float  f32x4  __attribute__((ext_vector_type(4)));

#define XSS 296   // xs row stride (bf16): 16B-aligned rows, odd 16B-units (37)
#define MS  136   // mid-buffer row stride (17 16B-units)
#define EDG 128   // edges per block

// ---------------- weight pack: row-major fp32 [K][N] -> bf16 MFMA fragments ----
// frag: lane l holds W[k = kt*32 + (l>>4)*8 + j][n = nt*16 + (l&15)].
// Used as the A-operand (= W^T in A-layout): D = W^T x X^T -> D[feat][edge].
__global__ void pack_weights(const float* __restrict__ We1, const float* __restrict__ We2,
                             const float* __restrict__ Wc1, const float* __restrict__ Wc2,
                             __bf16* __restrict__ pw1, __bf16* __restrict__ pw2,
                             __bf16* __restrict__ pwc1, __bf16* __restrict__ pwc2)
{
    int idx = blockIdx.x * 256 + threadIdx.x;   // 0 .. 71679
    const float* W; __bf16* P; int KT, Nr, local;
    if (idx < 36864)      { W = We1; P = pw1;  KT = 9; Nr = 128; local = idx; }
    else if (idx < 53248) { W = We2; P = pw2;  KT = 4; Nr = 128; local = idx - 36864; }
    else if (idx < 69632) { W = Wc1; P = pwc1; KT = 4; Nr = 128; local = idx - 53248; }
    else                  { W = Wc2; P = pwc2; KT = 4; Nr = 4;   local = idx - 69632; }
    int j = local & 7, lane = (local >> 3) & 63, rest = local >> 9;
    int kt = rest % KT, nt = rest / KT;
    int k = kt * 32 + (lane >> 4) * 8 + j;
    int n = nt * 16 + (lane & 15);
    float v = (n < Nr) ? W[k * Nr + n] : 0.f;
    P[local] = (__bf16)v;
}

// ---------------- CSR build ----------------
__global__ void hist_kernel(const int* __restrict__ ei, int* __restrict__ csr_cnt)
{
    int i = blockIdx.x * 256 + threadIdx.x;
    if (i < NE_) atomicAdd(&csr_cnt[ei[i]], 1);
}

__global__ void scan_kernel(const int* __restrict__ csr_cnt,
                            int* __restrict__ csr_off, int* __restrict__ csr_pos)
{
    __shared__ int part[256];
    const int t = threadIdx.x;
    int sum = 0;
    #pragma unroll
    for (int j = 0; j < 20; j++) {
        int idx = t * 20 + j;
        if (idx < NN_) sum += csr_cnt[idx];
    }
    part[t] = sum;
    __syncthreads();
    if (t == 0) {
        int run = 0;
        for (int i = 0; i < 256; i++) { int v = part[i]; part[i] = run; run += v; }
    }
    __syncthreads();
    int run = part[t];
    #pragma unroll
    for (int j = 0; j < 20; j++) {
        int idx = t * 20 + j;
        if (idx < NN_) { csr_off[idx] = run; csr_pos[idx] = run; run += csr_cnt[idx]; }
    }
    if (t == 0) csr_off[NN_] = NE_;
}

__global__ void bucket_kernel(const int* __restrict__ ei,
                              int* __restrict__ csr_pos, int* __restrict__ bucket)
{
    int i = blockIdx.x * 256 + threadIdx.x;
    if (i < NE_) { int p = atomicAdd(&csr_pos[ei[i]], 1); bucket[p] = i; }
}

// ---------------- h -> bf16 ----------------
__global__ void h2b_kernel(const float* __restrict__ h, __bf16* __restrict__ hb16)
{
    int i = blockIdx.x * 256 + threadIdx.x;
    if (i < B * NN_ * F / 4) {
        float4 v = ((const float4*)h)[i];
        bf16x4 bv = {(__bf16)v.x, (__bf16)v.y, (__bf16)v.z, (__bf16)v.w};
        ((bf16x4*)hb16)[i] = bv;
    }
}

// ---------------- edge_attr -> bf16, permuted into sorted (bucket) order -------
__global__ void ea_sort_kernel(const float* __restrict__ ea, const int* __restrict__ bucket,
                               __bf16* __restrict__ eas)
{
    int idx = blockIdx.x * 256 + threadIdx.x;
    if (idx < NE_ * 4) {
        int p = idx >> 2, j = idx & 3;
        int e = bucket[p];
        float4 v = ((const float4*)ea)[e * 4 + j];
        bf16x4 bv = {(__bf16)v.x, (__bf16)v.y, (__bf16)v.z, (__bf16)v.w};
        *(bf16x4*)&eas[p * 16 + j * 4] = bv;
    }
}

// ------- edge kernel: 128 edges, 8 waves, swapped-operand MFMA, seg-reduce ----
__global__ __launch_bounds__(512, 4) void edge_kernel(
    const __bf16* __restrict__ hb16, const float* __restrict__ coord,
    const int* __restrict__ ei, const __bf16* __restrict__ eas,
    const int* __restrict__ bucket,
    const float* __restrict__ be1, const float* __restrict__ be2,
    const float* __restrict__ bc1,
    const __bf16* __restrict__ pw1, const __bf16* __restrict__ pw2,
    const __bf16* __restrict__ pwc1, const __bf16* __restrict__ pwc2,
    float* __restrict__ agg_h, float* __restrict__ agg_c)
{
    // R: xs[128][296] (75776 B); buf1 aliases R[0:17408), buf2 = R[17408:34816)
    // (xs is dead once layer e1's MFMA reads complete - barrier separates).
    __shared__ __align__(16) __bf16 R[EDG * XSS];
    __shared__ __bf16 cds[EDG][12];
    __shared__ int rs[EDG], cs[EDG];

    const int t = threadIdx.x;            // 0..511
    const int b = blockIdx.y;
    const int p0 = blockIdx.x * EDG;      // sorted edge-slot base
    const int lane = t & 63, wave = t >> 6;   // wave 0..7 = nt tile
    const int quad = lane >> 4, c = lane & 15;

    if (t < EDG) {
        int eid = bucket[p0 + t];
        rs[t] = ei[eid]; cs[t] = ei[NE_ + eid];
    }
    __syncthreads();

    // ---- stage xs = [h_row | h_col] : 128 edges x 32 16B-chunks ----
    const __bf16* hb = hb16 + (size_t)b * NN_ * F;
    #pragma unroll
    for (int i = 0; i < 8; i++) {
        int e = i * 16 + (t >> 5);
        int ch = t & 31;
        int node = (ch < 16) ? rs[e] : cs[e];
        uint4 v = *(const uint4*)(hb + (size_t)node * F + (ch & 15) * 8);
        *(uint4*)&R[e * XSS + ch * 8] = v;
    }
    // ---- radial + ea (one thread per edge) ----
    if (t < EDG) {
        int e = t;
        const float* cr = coord + ((size_t)b * NN_ + rs[e]) * 12;
        const float* cc = coord + ((size_t)b * NN_ + cs[e]) * 12;
        float cd[12];
        #pragma unroll
        for (int j = 0; j < 12; j++) { cd[j] = cr[j] - cc[j]; cds[e][j] = (__bf16)cd[j]; }
        float prod[16]; float ss = 0.f;
        #pragma unroll
        for (int j = 0; j < 4; j++)
            #pragma unroll
            for (int k = 0; k < 4; k++) {
                float p = cd[j*3]*cd[k*3] + cd[j*3+1]*cd[k*3+1] + cd[j*3+2]*cd[k*3+2];
                prod[j*4 + k] = p; ss += p * p;
            }
        float inv = 1.0f / fmaxf(sqrtf(ss), 1e-12f);
        #pragma unroll
        for (int j = 0; j < 16; j++) R[e * XSS + 2*F + j] = (__bf16)(prod[j] * inv);
        const uint4* ep = (const uint4*)(eas + (size_t)(p0 + e) * 16);
        *(uint4*)&R[e * XSS + 2*F + 16] = ep[0];
        *(uint4*)&R[e * XSS + 2*F + 24] = ep[1];
    }
    __syncthreads();

    const bf16x8* pw1v  = (const bf16x8*)pw1;
    const bf16x8* pw2v  = (const bf16x8*)pw2;
    const bf16x8* pwc1v = (const bf16x8*)pwc1;
    const bf16x8* pwc2v = (const bf16x8*)pwc2;
    __bf16* buf1 = R;
    __bf16* buf2 = R + 17408;   // 128*136

    // ---- layer e1: D = We1^T x X^T. Wave owns nt=wave (1 weight frag per kt),
    //      iterates all 8 edge m-tiles. D[feat][edge]: col=edge, row=quad*4+i. ----
    f32x4 acc1[8];
    #pragma unroll
    for (int m = 0; m < 8; m++) acc1[m] = (f32x4){0.f, 0.f, 0.f, 0.f};
    for (int kt = 0; kt < 9; kt++) {
        bf16x8 w = pw1v[(wave*9 + kt)*64 + lane];
        #pragma unroll
        for (int m = 0; m < 8; m++) {
            bf16x8 x = *(const bf16x8*)&R[(m*16 + c) * XSS + kt*32 + quad*8];
            acc1[m] = __builtin_amdgcn_mfma_f32_16x16x32_bf16(w, x, acc1[m], 0, 0, 0);
        }
    }
    __syncthreads();   // all xs reads done; R (buf1) reusable
    {
        float4 bv = *(const float4*)&be1[wave*16 + quad*4];
        #pragma unroll
        for (int m = 0; m < 8; m++) {
            bf16x4 o = { (__bf16)fmaxf(acc1[m][0] + bv.x, 0.f),
                         (__bf16)fmaxf(acc1[m][1] + bv.y, 0.f),
                         (__bf16)fmaxf(acc1[m][2] + bv.z, 0.f),
                         (__bf16)fmaxf(acc1[m][3] + bv.w, 0.f) };
            *(bf16x4*)&buf1[(m*16 + c) * MS + wave*16 + quad*4] = o;   // b64 write
        }
    }
    __syncthreads();

    // ---- layer e2: h1 @ We2 -> ef (buf2) ----
    f32x4 acc2[8];
    #pragma unroll
    for (int m = 0; m < 8; m++) acc2[m] = (f32x4){0.f, 0.f, 0.f, 0.f};
    for (int kt = 0; kt < 4; kt++) {
        bf16x8 w = pw2v[(wave*4 + kt)*64 + lane];
        #pragma unroll
        for (int m = 0; m < 8; m++) {
            bf16x8 x = *(const bf16x8*)&buf1[(m*16 + c) * MS + kt*32 + quad*8];
            acc2[m] = __builtin_amdgcn_mfma_f32_16x16x32_bf16(w, x, acc2[m], 0, 0, 0);
        }
    }
    {
        float4 bv = *(const float4*)&be2[wave*16 + quad*4];
        #pragma unroll
        for (int m = 0; m < 8; m++) {
            bf16x4 o = { (__bf16)fmaxf(acc2[m][0] + bv.x, 0.f),
                         (__bf16)fmaxf(acc2[m][1] + bv.y, 0.f),
                         (__bf16)fmaxf(acc2[m][2] + bv.z, 0.f),
                         (__bf16)fmaxf(acc2[m][3] + bv.w, 0.f) };
            *(bf16x4*)&buf2[(m*16 + c) * MS + wave*16 + quad*4] = o;
        }
    }
    __syncthreads();

    // ---- coord layer c1: ef @ Wc1 -> buf1 ----
    f32x4 acc3[8];
    #pragma unroll
    for (int m = 0; m < 8; m++) acc3[m] = (f32x4){0.f, 0.f, 0.f, 0.f};
    for (int kt = 0; kt < 4; kt++) {
        bf16x8 w = pwc1v[(wave*4 + kt)*64 + lane];
        #pragma unroll
        for (int m = 0; m < 8; m++) {
            bf16x8 x = *(const bf16x8*)&buf2[(m*16 + c) * MS + kt*32 + quad*8];
            acc3[m] = __builtin_amdgcn_mfma_f32_16x16x32_bf16(w, x, acc3[m], 0, 0, 0);
        }
    }
    {
        float4 bv = *(const float4*)&bc1[wave*16 + quad*4];
        #pragma unroll
        for (int m = 0; m < 8; m++) {
            bf16x4 o = { (__bf16)fmaxf(acc3[m][0] + bv.x, 0.f),
                         (__bf16)fmaxf(acc3[m][1] + bv.y, 0.f),
                         (__bf16)fmaxf(acc3[m][2] + bv.z, 0.f),
                         (__bf16)fmaxf(acc3[m][3] + bv.w, 0.f) };
            *(bf16x4*)&buf1[(m*16 + c) * MS + wave*16 + quad*4] = o;
        }
    }
    __syncthreads();

    // ---- coord layer c2 (M-split: wave owns m-tile=wave). D rows 0..3 = feats. ----
    f32x4 accw = (f32x4){0.f, 0.f, 0.f, 0.f};
    for (int kt = 0; kt < 4; kt++) {
        bf16x8 w = pwc2v[kt*64 + lane];
        bf16x8 x = *(const bf16x8*)&buf1[(wave*16 + c) * MS + kt*32 + quad*8];
        accw = __builtin_amdgcn_mfma_f32_16x16x32_bf16(w, x, accw, 0, 0, 0);
    }
    // trans = cd * w: lane (quad==0, col c) owns all 4 w's for edge wave*16+c
    if (quad == 0) {
        int e = wave*16 + c;
        #pragma unroll
        for (int j = 0; j < 12; j++)
            cds[e][j] = (__bf16)((float)cds[e][j] * accw[j/3]);
    }
    __syncthreads();

    // ---- segmented reduction over sorted rows -> few atomics ----
    {
        float* aggh_b = agg_h + (size_t)b * NN_ * HID;
        const int col = t & 127, seg = t >> 7;    // 4 segments x 32 edges
        float run = 0.f;
        int cur = rs[seg * 32];
        for (int e = seg * 32; e < seg * 32 + 32; e++) {
            int r = rs[e];
            float v = (float)buf2[e * MS + col];
            if (r != cur) {
                atomicAdd(&aggh_b[(size_t)cur * HID + col], run);
                run = 0.f; cur = r;
            }
            run += v;
        }
        atomicAdd(&aggh_b[(size_t)cur * HID + col], run);
    }
    if (t < 96) {
        float* aggc_b = agg_c + (size_t)b * NN_ * 12;
        const int j = t % 12, q = t / 12;         // 8 segments x 16 edges
        float run = 0.f;
        int cur = rs[q * 16];
        for (int e = q * 16; e < q * 16 + 16; e++) {
            int r = rs[e];
            float v = (float)cds[e][j];
            if (r != cur) {
                atomicAdd(&aggc_b[(size_t)cur * 12 + j], run);
                run = 0.f; cur = r;
            }
            run += v;
        }
        atomicAdd(&aggc_b[(size_t)cur * 12 + j], run);
    }
}

// ---------------- node kernel (reads precomputed agg_h) ----------------
#define NPB 8
__global__ __launch_bounds__(128) void node_kernel(
    const float* __restrict__ h, const float* __restrict__ agg_h,
    const float* __restrict__ Wn1, const float* __restrict__ bn1,
    const float* __restrict__ Wn2, const float* __restrict__ bn2,
    float* __restrict__ out_h)
{
    __shared__ float zs[NPB][2 * F];
    __shared__ float h1[NPB][HID];
    const int t  = threadIdx.x;
    const int b  = blockIdx.y;
    const int n0 = blockIdx.x * NPB;

    #pragma unroll
    for (int i = 0; i < NPB; i++) {
        size_t base = ((size_t)b * NN_ + n0 + i);
        zs[i][t]     = h[base * F + t];
        zs[i][F + t] = agg_h[base * HID + t];
    }
    __syncthreads();

    float acc[NPB];
    #pragma unroll
    for (int i = 0; i < NPB; i++) acc[i] = bn1[t];
    for (int k = 0; k < 2 * F; k += 4) {
        float w0 = Wn1[(k+0)*HID + t], w1 = Wn1[(k+1)*HID + t];
        float w2 = Wn1[(k+2)*HID + t], w3 = Wn1[(k+3)*HID + t];
        #pragma unroll
        for (int i = 0; i < NPB; i++) {
            float4 xv = *(const float4*)&zs[i][k];
            acc[i] += xv.x*w0 + xv.y*w1 + xv.z*w2 + xv.w*w3;
        }
    }
    __syncthreads();
    #pragma unroll
    for (int i = 0; i < NPB; i++) h1[i][t] = fmaxf(acc[i], 0.f);
    __syncthreads();

    #pragma unroll
    for (int i = 0; i < NPB; i++) acc[i] = bn2[t];
    for (int k = 0; k < HID; k += 4) {
        float w0 = Wn2[(k+0)*F + t], w1 = Wn2[(k+1)*F + t];
        float w2 = Wn2[(k+2)*F + t], w3 = Wn2[(k+3)*F + t];
        #pragma unroll
        for (int i = 0; i < NPB; i++) {
            float4 xv = *(const float4*)&h1[i][k];
            acc[i] += xv.x*w0 + xv.y*w1 + xv.z*w2 + xv.w*w3;
        }
    }
    #pragma unroll
    for (int i = 0; i < NPB; i++) {
        size_t base = ((size_t)b * NN_ + n0 + i);
        out_h[base * F + t] = zs[i][t] + acc[i];
    }
}

// ---------------- coord kernel (degree from csr_off) ----------------
__global__ void coord_kernel(
    const float* __restrict__ coord, const float* __restrict__ agg_c,
    const int* __restrict__ csr_off, float* __restrict__ out_c)
{
    int i = blockIdx.x * 256 + threadIdx.x;
    if (i < B * NN_ * 12) {
        int node = i / 12;
        int n = node % NN_;
        float deg = (float)(csr_off[n + 1] - csr_off[n]);
        out_c[i] = coord[i] + agg_c[i] / fmaxf(deg, 1.0f);
    }
}

extern "C" void kernel_launch(void* const* d_in, const int* in_sizes, int n_in,
                              void* d_out, int out_size, void* d_ws, size_t ws_size,
                              hipStream_t stream) {
    const float* h     = (const float*)d_in[0];
    const float* coord = (const float*)d_in[1];
    const int*   ei    = (const int*)d_in[2];
    const float* ea    = (const float*)d_in[3];
    const float* We1   = (const float*)d_in[4];
    const float* be1   = (const float*)d_in[5];
    const float* We2   = (const float*)d_in[6];
    const float* be2   = (const float*)d_in[7];
    const float* Wn1   = (const float*)d_in[8];
    const float* bn1   = (const float*)d_in[9];
    const float* Wn2   = (const float*)d_in[10];
    const float* bn2   = (const float*)d_in[11];
    const float* Wc1   = (const float*)d_in[12];
    const float* bc1   = (const float*)d_in[13];
    const float* Wc2   = (const float*)d_in[14];

    float* out_h = (float*)d_out;                       // [B,N,F]
    float* out_c = out_h + (size_t)B * NN_ * F;         // [B,N,4,3]

    unsigned char* base = (unsigned char*)d_ws;
    __bf16* pw1  = (__bf16*)base;             // 36864 bf16
    __bf16* pw2  = pw1 + 36864;               // 16384
    __bf16* pwc1 = pw2 + 16384;               // 16384
    __bf16* pwc2 = pwc1 + 16384;              // 2048  -> 143360 B total
    unsigned char* dyn = base + 143360;

    int* csr_cnt = (int*)(dyn);               // 20000 B
    int* csr_off = (int*)(dyn + 20000);       // 20016 B
    int* csr_pos = (int*)(dyn + 40016);       // 20000 B
    int* bucket  = (int*)(dyn + 60016);       // 640000 B
    float* agg_h = (float*)(dyn + 700016);    // [B,N,HID]  5,120,000 B
    float* agg_c = agg_h + (size_t)B * NN_ * HID;      // [B,N,12] 480,000 B
    __bf16* hb16 = (__bf16*)(agg_c + (size_t)B * NN_ * 12);  // 2,560,000 B
    __bf16* eas  = hb16 + (size_t)B * NN_ * F;               // 5,120,000 B

    pack_weights<<<280, 256, 0, stream>>>(We1, We2, Wc1, Wc2, pw1, pw2, pwc1, pwc2);

    hipMemsetAsync(csr_cnt, 0, 20000, stream);
    hipMemsetAsync(agg_h, 0, (size_t)B * NN_ * (HID + 12) * sizeof(float), stream);

    hist_kernel<<<625, 256, 0, stream>>>(ei, csr_cnt);
    scan_kernel<<<1, 256, 0, stream>>>(csr_cnt, csr_off, csr_pos);
    bucket_kernel<<<625, 256, 0, stream>>>(ei, csr_pos, bucket);
    h2b_kernel<<<1250, 256, 0, stream>>>(h, hb16);
    ea_sort_kernel<<<2500, 256, 0, stream>>>(ea, bucket, eas);

    dim3 eg(NE_ / EDG, B);   // 1250 x 2
    edge_kernel<<<eg, 512, 0, stream>>>(hb16, coord, ei, eas, bucket, be1, be2, bc1,
                                        pw1, pw2, pwc1, pwc2, agg_h, agg_c);

    dim3 ng(NN_ / NPB, B);   // 625 x 2
    node_kernel<<<ng, 128, 0, stream>>>(h, agg_h, Wn1, bn1, Wn2, bn2, out_h);

    int cn = (B * NN_ * 12 + 255) / 256;
    coord_kernel<<<cn, 256, 0, stream>>>(coord, agg_c, csr_off, out_c);
}

// Round 7
// 236.647 us; speedup vs baseline: 1.7835x; 1.0868x over previous
//
#include <hip/hip_runtime.h>
#include <hip/hip_bf16.h>

#define B   2
#define NN_ 5000
#define NE_ 160000
#define F   128
#define HID 128
#define ED  16

typedef __bf16 bf16x8 __attribute__((ext_vector_type(8)));
typedef __bf16 bf16x4 __attribute__((ext_vector_type(4)));
typedef float  f32x4  __attribute__((ext_vector_type(4)));

#define MS  136   // buf row stride (17 16B-units, odd -> conflict-free b128)
#define PS  40    // xs32 row stride (80B = 20 dwords -> 2-way, free)
#define EDG 128   // edges per block

// ---------------- weight pack: row-major fp32 [K][N] -> bf16 MFMA fragments ----
// frag: lane l holds W[k = kt*32 + (l>>4)*8 + j][n = nt*16 + (l&15)]; used as
// A-operand (W^T): D = W^T x X^T -> D[feat][edge] (col=edge, row=quad*4+i).
__global__ void pack_weights(const float* __restrict__ We1, const float* __restrict__ We2,
                             const float* __restrict__ Wc1, const float* __restrict__ Wc2,
                             __bf16* __restrict__ pw1, __bf16* __restrict__ pw2,
                             __bf16* __restrict__ pwc1, __bf16* __restrict__ pwc2)
{
    int idx = blockIdx.x * 256 + threadIdx.x;   // 0 .. 71679
    const float* W; __bf16* P; int KT, Nr, local;
    if (idx < 36864)      { W = We1; P = pw1;  KT = 9; Nr = 128; local = idx; }
    else if (idx < 53248) { W = We2; P = pw2;  KT = 4; Nr = 128; local = idx - 36864; }
    else if (idx < 69632) { W = Wc1; P = pwc1; KT = 4; Nr = 128; local = idx - 53248; }
    else                  { W = Wc2; P = pwc2; KT = 4; Nr = 4;   local = idx - 69632; }
    int j = local & 7, lane = (local >> 3) & 63, rest = local >> 9;
    int kt = rest % KT, nt = rest / KT;
    int k = kt * 32 + (lane >> 4) * 8 + j;
    int n = nt * 16 + (lane & 15);
    float v = (n < Nr) ? W[k * Nr + n] : 0.f;
    P[local] = (__bf16)v;
}

// ---------------- CSR build ----------------
__global__ void hist_kernel(const int* __restrict__ ei, int* __restrict__ csr_cnt)
{
    int i = blockIdx.x * 256 + threadIdx.x;
    if (i < NE_) atomicAdd(&csr_cnt[ei[i]], 1);
}

__global__ void scan_kernel(const int* __restrict__ csr_cnt,
                            int* __restrict__ csr_off, int* __restrict__ csr_pos)
{
    __shared__ int part[256];
    const int t = threadIdx.x;
    int sum = 0;
    #pragma unroll
    for (int j = 0; j < 20; j++) {
        int idx = t * 20 + j;
        if (idx < NN_) sum += csr_cnt[idx];
    }
    part[t] = sum;
    __syncthreads();
    if (t == 0) {
        int run = 0;
        for (int i = 0; i < 256; i++) { int v = part[i]; part[i] = run; run += v; }
    }
    __syncthreads();
    int run = part[t];
    #pragma unroll
    for (int j = 0; j < 20; j++) {
        int idx = t * 20 + j;
        if (idx < NN_) { csr_off[idx] = run; csr_pos[idx] = run; run += csr_cnt[idx]; }
    }
    if (t == 0) csr_off[NN_] = NE_;
}

__global__ void bucket_kernel(const int* __restrict__ ei,
                              int* __restrict__ csr_pos, int* __restrict__ bucket)
{
    int i = blockIdx.x * 256 + threadIdx.x;
    if (i < NE_) { int p = atomicAdd(&csr_pos[ei[i]], 1); bucket[p] = i; }
}

// ---------------- edge_attr -> bf16, permuted into sorted (bucket) order -------
__global__ void ea_sort_kernel(const float* __restrict__ ea, const int* __restrict__ bucket,
                               __bf16* __restrict__ eas)
{
    int idx = blockIdx.x * 256 + threadIdx.x;
    if (idx < NE_ * 4) {
        int p = idx >> 2, j = idx & 3;
        int e = bucket[p];
        float4 v = ((const float4*)ea)[e * 4 + j];
        bf16x4 bv = {(__bf16)v.x, (__bf16)v.y, (__bf16)v.z, (__bf16)v.w};
        *(bf16x4*)&eas[p * 16 + j * 4] = bv;
    }
}

// ------- pre kernel: per-node P_r = h @ We1[0:128], P_c = h @ We1[128:256] ------
__global__ __launch_bounds__(512) void pre_kernel(
    const float* __restrict__ h, const __bf16* __restrict__ pw1,
    __bf16* __restrict__ pr, __bf16* __restrict__ pc)
{
    __shared__ __align__(16) __bf16 hs[128 * MS];
    const int t = threadIdx.x;
    const int b = blockIdx.y;
    const int n0 = blockIdx.x * 128;
    const int lane = t & 63, wave = t >> 6;   // wave = nt (8 feat-tiles)
    const int quad = lane >> 4, c = lane & 15;

    // stage h rows n0..n0+127 as bf16 (guarded)
    #pragma unroll
    for (int it = 0; it < 8; it++) {
        int idx = it * 512 + t;               // 0..4095
        int node = idx >> 5, ch = idx & 31;   // 32 float4-chunks per row
        int gn = n0 + node;
        float4 v = (gn < NN_) ? *(const float4*)&h[((size_t)b * NN_ + gn) * F + ch * 4]
                              : (float4){0.f, 0.f, 0.f, 0.f};
        bf16x4 bv = {(__bf16)v.x, (__bf16)v.y, (__bf16)v.z, (__bf16)v.w};
        *(bf16x4*)&hs[node * MS + ch * 4] = bv;
    }
    __syncthreads();

    const bf16x8* pw1v = (const bf16x8*)pw1;
    f32x4 accr[8], accc[8];
    #pragma unroll
    for (int m = 0; m < 8; m++) { accr[m] = (f32x4){0,0,0,0}; accc[m] = (f32x4){0,0,0,0}; }
    for (int kt = 0; kt < 4; kt++) {
        bf16x8 wr = pw1v[(wave * 9 + kt) * 64 + lane];       // We1 rows 0..127
        bf16x8 wc = pw1v[(wave * 9 + kt + 4) * 64 + lane];   // We1 rows 128..255
        #pragma unroll
        for (int m = 0; m < 8; m++) {
            bf16x8 x = *(const bf16x8*)&hs[(m * 16 + c) * MS + kt * 32 + quad * 8];
            accr[m] = __builtin_amdgcn_mfma_f32_16x16x32_bf16(wr, x, accr[m], 0, 0, 0);
            accc[m] = __builtin_amdgcn_mfma_f32_16x16x32_bf16(wc, x, accc[m], 0, 0, 0);
        }
    }
    #pragma unroll
    for (int m = 0; m < 8; m++) {
        int gn = n0 + m * 16 + c;
        if (gn < NN_) {
            size_t base = ((size_t)b * NN_ + gn) * F + wave * 16 + quad * 4;
            bf16x4 orr = {(__bf16)accr[m][0], (__bf16)accr[m][1], (__bf16)accr[m][2], (__bf16)accr[m][3]};
            bf16x4 occ = {(__bf16)accc[m][0], (__bf16)accc[m][1], (__bf16)accc[m][2], (__bf16)accc[m][3]};
            *(bf16x4*)&pr[base] = orr;
            *(bf16x4*)&pc[base] = occ;
        }
    }
}

// ------- edge kernel: presum + K=32 e1, MFMA chain, seg-reduce -------
// wave -> (mh = wave>>2: half of the 8 edge m-tiles; np = wave&3: nt pair)
__global__ __launch_bounds__(512, 4) void edge_kernel(
    const __bf16* __restrict__ pr, const __bf16* __restrict__ pc,
    const float* __restrict__ coord,
    const int* __restrict__ ei, const __bf16* __restrict__ eas,
    const int* __restrict__ bucket,
    const float* __restrict__ be1, const float* __restrict__ be2,
    const float* __restrict__ bc1,
    const __bf16* __restrict__ pw1, const __bf16* __restrict__ pw2,
    const __bf16* __restrict__ pwc1, const __bf16* __restrict__ pwc2,
    float* __restrict__ agg_h, float* __restrict__ agg_c)
{
    __shared__ __align__(16) __bf16 buf1[EDG * MS];  // presum -> h1 -> h2
    __shared__ __align__(16) __bf16 buf2[EDG * MS];  // xs32 (stride PS) -> ef
    __shared__ __bf16 cds[EDG][12];
    __shared__ int rs[EDG], cs[EDG];

    const int t = threadIdx.x;            // 0..511
    const int b = blockIdx.y;
    const int p0 = blockIdx.x * EDG;
    const int lane = t & 63, wave = t >> 6;
    const int quad = lane >> 4, c = lane & 15;
    const int mh = wave >> 2, np = wave & 3;

    if (t < EDG) {
        int eid = bucket[p0 + t];
        rs[t] = ei[eid]; cs[t] = ei[NE_ + eid];
    }
    __syncthreads();

    // ---- stage presum = pr[row] + pc[col] into buf1 ----
    const __bf16* prb = pr + (size_t)b * NN_ * F;
    const __bf16* pcb = pc + (size_t)b * NN_ * F;
    #pragma unroll
    for (int it = 0; it < 4; it++) {
        int idx = it * 512 + t;           // 0..2047: 128 edges x 16 chunks of 8
        int e = idx >> 4, ch = idx & 15;
        bf16x8 a = *(const bf16x8*)(prb + (size_t)rs[e] * F + ch * 8);
        bf16x8 v = *(const bf16x8*)(pcb + (size_t)cs[e] * F + ch * 8);
        bf16x8 o;
        #pragma unroll
        for (int j = 0; j < 8; j++) o[j] = (__bf16)((float)a[j] + (float)v[j]);
        *(bf16x8*)&buf1[e * MS + ch * 8] = o;
    }
    // ---- radial + ea -> xs32 (buf2 region, stride PS) ----
    if (t < EDG) {
        int e = t;
        const float* cr = coord + ((size_t)b * NN_ + rs[e]) * 12;
        const float* cc = coord + ((size_t)b * NN_ + cs[e]) * 12;
        float cd[12];
        #pragma unroll
        for (int j = 0; j < 12; j++) { cd[j] = cr[j] - cc[j]; cds[e][j] = (__bf16)cd[j]; }
        float prod[16]; float ss = 0.f;
        #pragma unroll
        for (int j = 0; j < 4; j++)
            #pragma unroll
            for (int k = 0; k < 4; k++) {
                float p = cd[j*3]*cd[k*3] + cd[j*3+1]*cd[k*3+1] + cd[j*3+2]*cd[k*3+2];
                prod[j*4 + k] = p; ss += p * p;
            }
        float inv = 1.0f / fmaxf(sqrtf(ss), 1e-12f);
        #pragma unroll
        for (int j = 0; j < 16; j++) buf2[e * PS + j] = (__bf16)(prod[j] * inv);
        const uint4* ep = (const uint4*)(eas + (size_t)(p0 + e) * 16);
        *(uint4*)&buf2[e * PS + 16] = ep[0];
        *(uint4*)&buf2[e * PS + 24] = ep[1];
    }
    __syncthreads();

    const bf16x8* pw1v  = (const bf16x8*)pw1;
    const bf16x8* pw2v  = (const bf16x8*)pw2;
    const bf16x8* pwc1v = (const bf16x8*)pwc1;
    const bf16x8* pwc2v = (const bf16x8*)pwc2;

    // ---- e1: K=32 (kt=8 of pw1) + presum + bias ----
    f32x4 acc1[4][2];
    #pragma unroll
    for (int m = 0; m < 4; m++)
        #pragma unroll
        for (int n = 0; n < 2; n++) acc1[m][n] = (f32x4){0,0,0,0};
    {
        bf16x8 x1[4];
        #pragma unroll
        for (int m = 0; m < 4; m++)
            x1[m] = *(const bf16x8*)&buf2[((mh*4 + m)*16 + c) * PS + quad*8];
        #pragma unroll
        for (int n = 0; n < 2; n++) {
            bf16x8 w = pw1v[((2*np + n)*9 + 8)*64 + lane];
            #pragma unroll
            for (int m = 0; m < 4; m++)
                acc1[m][n] = __builtin_amdgcn_mfma_f32_16x16x32_bf16(w, x1[m], acc1[m][n], 0, 0, 0);
        }
    }
    #pragma unroll
    for (int n = 0; n < 2; n++) {
        int nt = 2*np + n;
        float4 bb = *(const float4*)&be1[nt*16 + quad*4];
        #pragma unroll
        for (int m = 0; m < 4; m++) {
            int row = (mh*4 + m)*16 + c;
            bf16x4 p = *(const bf16x4*)&buf1[row * MS + nt*16 + quad*4];
            bf16x4 o = { (__bf16)fmaxf(acc1[m][n][0] + (float)p[0] + bb.x, 0.f),
                         (__bf16)fmaxf(acc1[m][n][1] + (float)p[1] + bb.y, 0.f),
                         (__bf16)fmaxf(acc1[m][n][2] + (float)p[2] + bb.z, 0.f),
                         (__bf16)fmaxf(acc1[m][n][3] + (float)p[3] + bb.w, 0.f) };
            *(bf16x4*)&buf1[row * MS + nt*16 + quad*4] = o;
        }
    }
    __syncthreads();

    // ---- e2: h1 @ We2 -> ef (buf2, stride MS) ----
    f32x4 acc2[4][2];
    #pragma unroll
    for (int m = 0; m < 4; m++)
        #pragma unroll
        for (int n = 0; n < 2; n++) acc2[m][n] = (f32x4){0,0,0,0};
    for (int kt = 0; kt < 4; kt++) {
        bf16x8 x[4];
        #pragma unroll
        for (int m = 0; m < 4; m++)
            x[m] = *(const bf16x8*)&buf1[((mh*4 + m)*16 + c) * MS + kt*32 + quad*8];
        #pragma unroll
        for (int n = 0; n < 2; n++) {
            bf16x8 w = pw2v[((2*np + n)*4 + kt)*64 + lane];
            #pragma unroll
            for (int m = 0; m < 4; m++)
                acc2[m][n] = __builtin_amdgcn_mfma_f32_16x16x32_bf16(w, x[m], acc2[m][n], 0, 0, 0);
        }
    }
    #pragma unroll
    for (int n = 0; n < 2; n++) {
        int nt = 2*np + n;
        float4 bb = *(const float4*)&be2[nt*16 + quad*4];
        #pragma unroll
        for (int m = 0; m < 4; m++) {
            int row = (mh*4 + m)*16 + c;
            bf16x4 o = { (__bf16)fmaxf(acc2[m][n][0] + bb.x, 0.f),
                         (__bf16)fmaxf(acc2[m][n][1] + bb.y, 0.f),
                         (__bf16)fmaxf(acc2[m][n][2] + bb.z, 0.f),
                         (__bf16)fmaxf(acc2[m][n][3] + bb.w, 0.f) };
            *(bf16x4*)&buf2[row * MS + nt*16 + quad*4] = o;
        }
    }
    __syncthreads();

    // ---- c1: ef @ Wc1 -> buf1 ----
    f32x4 acc3[4][2];
    #pragma unroll
    for (int m = 0; m < 4; m++)
        #pragma unroll
        for (int n = 0; n < 2; n++) acc3[m][n] = (f32x4){0,0,0,0};
    for (int kt = 0; kt < 4; kt++) {
        bf16x8 x[4];
        #pragma unroll
        for (int m = 0; m < 4; m++)
            x[m] = *(const bf16x8*)&buf2[((mh*4 + m)*16 + c) * MS + kt*32 + quad*8];
        #pragma unroll
        for (int n = 0; n < 2; n++) {
            bf16x8 w = pwc1v[((2*np + n)*4 + kt)*64 + lane];
            #pragma unroll
            for (int m = 0; m < 4; m++)
                acc3[m][n] = __builtin_amdgcn_mfma_f32_16x16x32_bf16(w, x[m], acc3[m][n], 0, 0, 0);
        }
    }
    #pragma unroll
    for (int n = 0; n < 2; n++) {
        int nt = 2*np + n;
        float4 bb = *(const float4*)&bc1[nt*16 + quad*4];
        #pragma unroll
        for (int m = 0; m < 4; m++) {
            int row = (mh*4 + m)*16 + c;
            bf16x4 o = { (__bf16)fmaxf(acc3[m][n][0] + bb.x, 0.f),
                         (__bf16)fmaxf(acc3[m][n][1] + bb.y, 0.f),
                         (__bf16)fmaxf(acc3[m][n][2] + bb.z, 0.f),
                         (__bf16)fmaxf(acc3[m][n][3] + bb.w, 0.f) };
            *(bf16x4*)&buf1[row * MS + nt*16 + quad*4] = o;
        }
    }
    __syncthreads();

    // ---- c2: wave owns edges wave*16..+15; valid feats in quad 0 ----
    f32x4 accw = (f32x4){0,0,0,0};
    for (int kt = 0; kt < 4; kt++) {
        bf16x8 x = *(const bf16x8*)&buf1[(wave*16 + c) * MS + kt*32 + quad*8];
        accw = __builtin_amdgcn_mfma_f32_16x16x32_bf16(pwc2v[kt*64 + lane], x, accw, 0, 0, 0);
    }
    if (quad == 0) {
        int e = wave*16 + c;
        #pragma unroll
        for (int j = 0; j < 12; j++)
            cds[e][j] = (__bf16)((float)cds[e][j] * accw[j/3]);
    }
    __syncthreads();

    // ---- segmented reduction over sorted rows -> few atomics ----
    {
        float* aggh_b = agg_h + (size_t)b * NN_ * HID;
        const int col = t & 127, seg = t >> 7;    // 4 segs x 32 edges
        float run = 0.f;
        int cur = rs[seg * 32];
        for (int e = seg * 32; e < seg * 32 + 32; e++) {
            int r = rs[e];
            float v = (float)buf2[e * MS + col];
            if (r != cur) {
                atomicAdd(&aggh_b[(size_t)cur * HID + col], run);
                run = 0.f; cur = r;
            }
            run += v;
        }
        atomicAdd(&aggh_b[(size_t)cur * HID + col], run);
    }
    if (t < 96) {
        float* aggc_b = agg_c + (size_t)b * NN_ * 12;
        const int j = t % 12, q = t / 12;         // 8 segs x 16 edges
        float run = 0.f;
        int cur = rs[q * 16];
        for (int e = q * 16; e < q * 16 + 16; e++) {
            int r = rs[e];
            float v = (float)cds[e][j];
            if (r != cur) {
                atomicAdd(&aggc_b[(size_t)cur * 12 + j], run);
                run = 0.f; cur = r;
            }
            run += v;
        }
        atomicAdd(&aggc_b[(size_t)cur * 12 + j], run);
    }
}

// ---------------- node kernel (reads precomputed agg_h) ----------------
#define NPB 8
__global__ __launch_bounds__(128) void node_kernel(
    const float* __restrict__ h, const float* __restrict__ agg_h,
    const float* __restrict__ Wn1, const float* __restrict__ bn1,
    const float* __restrict__ Wn2, const float* __restrict__ bn2,
    float* __restrict__ out_h)
{
    __shared__ float zs[NPB][2 * F];
    __shared__ float h1[NPB][HID];
    const int t  = threadIdx.x;
    const int b  = blockIdx.y;
    const int n0 = blockIdx.x * NPB;

    #pragma unroll
    for (int i = 0; i < NPB; i++) {
        size_t base = ((size_t)b * NN_ + n0 + i);
        zs[i][t]     = h[base * F + t];
        zs[i][F + t] = agg_h[base * HID + t];
    }
    __syncthreads();

    float acc[NPB];
    #pragma unroll
    for (int i = 0; i < NPB; i++) acc[i] = bn1[t];
    for (int k = 0; k < 2 * F; k += 4) {
        float w0 = Wn1[(k+0)*HID + t], w1 = Wn1[(k+1)*HID + t];
        float w2 = Wn1[(k+2)*HID + t], w3 = Wn1[(k+3)*HID + t];
        #pragma unroll
        for (int i = 0; i < NPB; i++) {
            float4 xv = *(const float4*)&zs[i][k];
            acc[i] += xv.x*w0 + xv.y*w1 + xv.z*w2 + xv.w*w3;
        }
    }
    __syncthreads();
    #pragma unroll
    for (int i = 0; i < NPB; i++) h1[i][t] = fmaxf(acc[i], 0.f);
    __syncthreads();

    #pragma unroll
    for (int i = 0; i < NPB; i++) acc[i] = bn2[t];
    for (int k = 0; k < HID; k += 4) {
        float w0 = Wn2[(k+0)*F + t], w1 = Wn2[(k+1)*F + t];
        float w2 = Wn2[(k+2)*F + t], w3 = Wn2[(k+3)*F + t];
        #pragma unroll
        for (int i = 0; i < NPB; i++) {
            float4 xv = *(const float4*)&h1[i][k];
            acc[i] += xv.x*w0 + xv.y*w1 + xv.z*w2 + xv.w*w3;
        }
    }
    #pragma unroll
    for (int i = 0; i < NPB; i++) {
        size_t base = ((size_t)b * NN_ + n0 + i);
        out_h[base * F + t] = zs[i][t] + acc[i];
    }
}

// ---------------- coord kernel (degree from csr_off) ----------------
__global__ void coord_kernel(
    const float* __restrict__ coord, const float* __restrict__ agg_c,
    const int* __restrict__ csr_off, float* __restrict__ out_c)
{
    int i = blockIdx.x * 256 + threadIdx.x;
    if (i < B * NN_ * 12) {
        int node = i / 12;
        int n = node % NN_;
        float deg = (float)(csr_off[n + 1] - csr_off[n]);
        out_c[i] = coord[i] + agg_c[i] / fmaxf(deg, 1.0f);
    }
}

extern "C" void kernel_launch(void* const* d_in, const int* in_sizes, int n_in,
                              void* d_out, int out_size, void* d_ws, size_t ws_size,
                              hipStream_t stream) {
    const float* h     = (const float*)d_in[0];
    const float* coord = (const float*)d_in[1];
    const int*   ei    = (const int*)d_in[2];
    const float* ea    = (const float*)d_in[3];
    const float* We1   = (const float*)d_in[4];
    const float* be1   = (const float*)d_in[5];
    const float* We2   = (const float*)d_in[6];
    const float* be2   = (const float*)d_in[7];
    const float* Wn1   = (const float*)d_in[8];
    const float* bn1   = (const float*)d_in[9];
    const float* Wn2   = (const float*)d_in[10];
    const float* bn2   = (const float*)d_in[11];
    const float* Wc1   = (const float*)d_in[12];
    const float* bc1   = (const float*)d_in[13];
    const float* Wc2   = (const float*)d_in[14];

    float* out_h = (float*)d_out;                       // [B,N,F]
    float* out_c = out_h + (size_t)B * NN_ * F;         // [B,N,4,3]

    unsigned char* base = (unsigned char*)d_ws;
    __bf16* pw1  = (__bf16*)base;             // 36864 bf16
    __bf16* pw2  = pw1 + 36864;               // 16384
    __bf16* pwc1 = pw2 + 16384;               // 16384
    __bf16* pwc2 = pwc1 + 16384;              // 2048  -> 143360 B total
    unsigned char* dyn = base + 143360;

    int* csr_cnt = (int*)(dyn);               // 20000 B
    int* csr_off = (int*)(dyn + 20000);       // 20016 B
    int* csr_pos = (int*)(dyn + 40016);       // 20000 B
    int* bucket  = (int*)(dyn + 60016);       // 640000 B
    float* agg_h = (float*)(dyn + 700016);    // [B,N,HID]  5,120,000 B
    float* agg_c = agg_h + (size_t)B * NN_ * HID;      // [B,N,12] 480,000 B
    __bf16* pr   = (__bf16*)(agg_c + (size_t)B * NN_ * 12);  // 2,560,000 B
    __bf16* pc   = pr + (size_t)B * NN_ * F;                 // 2,560,000 B
    __bf16* eas  = pc + (size_t)B * NN_ * F;                 // 5,120,000 B

    pack_weights<<<280, 256, 0, stream>>>(We1, We2, Wc1, Wc2, pw1, pw2, pwc1, pwc2);

    hipMemsetAsync(csr_cnt, 0, 20000, stream);
    hipMemsetAsync(agg_h, 0, (size_t)B * NN_ * (HID + 12) * sizeof(float), stream);

    hist_kernel<<<625, 256, 0, stream>>>(ei, csr_cnt);
    scan_kernel<<<1, 256, 0, stream>>>(csr_cnt, csr_off, csr_pos);
    bucket_kernel<<<625, 256, 0, stream>>>(ei, csr_pos, bucket);

    dim3 pg((NN_ + 127) / 128, B);   // 40 x 2
    pre_kernel<<<pg, 512, 0, stream>>>(h, pw1, pr, pc);

    ea_sort_kernel<<<2500, 256, 0, stream>>>(ea, bucket, eas);

    dim3 eg(NE_ / EDG, B);   // 1250 x 2
    edge_kernel<<<eg, 512, 0, stream>>>(pr, pc, coord, ei, eas, bucket, be1, be2, bc1,
                                        pw1, pw2, pwc1, pwc2, agg_h, agg_c);

    dim3 ng(NN_ / NPB, B);   // 625 x 2
    node_kernel<<<ng, 128, 0, stream>>>(h, agg_h, Wn1, bn1, Wn2, bn2, out_h);

    int cn = (B * NN_ * 12 + 255) / 256;
    coord_kernel<<<cn, 256, 0, stream>>>(coord, agg_c, csr_off, out_c);
}

// Round 8
// 208.477 us; speedup vs baseline: 2.0244x; 1.1351x over previous
//
#include <hip/hip_runtime.h>
#include <hip/hip_bf16.h>

#define B   2
#define NN_ 5000
#define NE_ 160000
#define F   128
#define HID 128
#define ED  16

typedef __bf16 bf16x8 __attribute__((ext_vector_type(8)));
typedef __bf16 bf16x4 __attribute__((ext_vector_type(4)));
typedef float  f32x4  __attribute__((ext_vector_type(4)));

#define MS  136   // edge buf row stride (17 16B-units, odd -> conflict-free b128)
#define PS  40    // xs32 row stride
#define EDG 128   // edges per block
#define ZS  264   // node z row stride bf16 (33 16B-units, odd)
#define HS  136   // node h1 row stride
#define NPB2 32   // nodes per block

// ---------------- weight pack: row-major fp32 [K][N] -> bf16 MFMA fragments ----
// frag: lane l holds W[k = kt*32 + (l>>4)*8 + j][n = nt*16 + (l&15)]; used as
// A-operand (W^T): D = W^T x X^T -> D[feat][edge] (col=edge, row=quad*4+i).
__global__ void pack_weights(const float* __restrict__ We1, const float* __restrict__ We2,
                             const float* __restrict__ Wc1, const float* __restrict__ Wc2,
                             const float* __restrict__ Wn1, const float* __restrict__ Wn2,
                             __bf16* __restrict__ pw1, __bf16* __restrict__ pw2,
                             __bf16* __restrict__ pwc1, __bf16* __restrict__ pwc2,
                             __bf16* __restrict__ pwn1, __bf16* __restrict__ pwn2)
{
    int idx = blockIdx.x * 256 + threadIdx.x;   // 0 .. 120831
    const float* W; __bf16* P; int KT, Nr, local;
    if (idx < 36864)       { W = We1; P = pw1;  KT = 9; Nr = 128; local = idx; }
    else if (idx < 53248)  { W = We2; P = pw2;  KT = 4; Nr = 128; local = idx - 36864; }
    else if (idx < 69632)  { W = Wc1; P = pwc1; KT = 4; Nr = 128; local = idx - 53248; }
    else if (idx < 71680)  { W = Wc2; P = pwc2; KT = 4; Nr = 4;   local = idx - 69632; }
    else if (idx < 104448) { W = Wn1; P = pwn1; KT = 8; Nr = 128; local = idx - 71680; }
    else                   { W = Wn2; P = pwn2; KT = 4; Nr = 128; local = idx - 104448; }
    int j = local & 7, lane = (local >> 3) & 63, rest = local >> 9;
    int kt = rest % KT, nt = rest / KT;
    int k = kt * 32 + (lane >> 4) * 8 + j;
    int n = nt * 16 + (lane & 15);
    float v = (n < Nr) ? W[k * Nr + n] : 0.f;
    P[local] = (__bf16)v;
}

// ---------------- CSR build ----------------
__global__ void hist_kernel(const int* __restrict__ ei, int* __restrict__ csr_cnt)
{
    int i = blockIdx.x * 256 + threadIdx.x;
    if (i < NE_) atomicAdd(&csr_cnt[ei[i]], 1);
}

__global__ void scan_kernel(const int* __restrict__ csr_cnt,
                            int* __restrict__ csr_off, int* __restrict__ csr_pos)
{
    __shared__ int part[256];
    const int t = threadIdx.x;
    int sum = 0;
    #pragma unroll
    for (int j = 0; j < 20; j++) {
        int idx = t * 20 + j;
        if (idx < NN_) sum += csr_cnt[idx];
    }
    part[t] = sum;
    __syncthreads();
    if (t == 0) {
        int run = 0;
        for (int i = 0; i < 256; i++) { int v = part[i]; part[i] = run; run += v; }
    }
    __syncthreads();
    int run = part[t];
    #pragma unroll
    for (int j = 0; j < 20; j++) {
        int idx = t * 20 + j;
        if (idx < NN_) { csr_off[idx] = run; csr_pos[idx] = run; run += csr_cnt[idx]; }
    }
    if (t == 0) csr_off[NN_] = NE_;
}

// bucket + ea-permute fused: one pass, writes sorted-slot edge id AND sorted bf16 ea
__global__ void bucket_kernel(const int* __restrict__ ei, const float* __restrict__ ea,
                              int* __restrict__ csr_pos, int* __restrict__ bucket,
                              __bf16* __restrict__ eas)
{
    int i = blockIdx.x * 256 + threadIdx.x;
    if (i < NE_) {
        int p = atomicAdd(&csr_pos[ei[i]], 1);
        bucket[p] = i;
        const float4* src = (const float4*)(ea + (size_t)i * ED);
        __bf16* dst = eas + (size_t)p * ED;
        #pragma unroll
        for (int j = 0; j < 4; j++) {
            float4 v = src[j];
            bf16x4 bv = {(__bf16)v.x, (__bf16)v.y, (__bf16)v.z, (__bf16)v.w};
            *(bf16x4*)&dst[j * 4] = bv;
        }
    }
}

// ------- pre kernel: per-node P_r = h @ We1[0:128], P_c = h @ We1[128:256] ------
__global__ __launch_bounds__(512) void pre_kernel(
    const float* __restrict__ h, const __bf16* __restrict__ pw1,
    __bf16* __restrict__ pr, __bf16* __restrict__ pc)
{
    __shared__ __align__(16) __bf16 hs[128 * MS];
    const int t = threadIdx.x;
    const int b = blockIdx.y;
    const int n0 = blockIdx.x * 128;
    const int lane = t & 63, wave = t >> 6;   // wave = nt (8 feat-tiles)
    const int quad = lane >> 4, c = lane & 15;

    #pragma unroll
    for (int it = 0; it < 8; it++) {
        int idx = it * 512 + t;               // 0..4095
        int node = idx >> 5, ch = idx & 31;
        int gn = n0 + node;
        float4 v = (gn < NN_) ? *(const float4*)&h[((size_t)b * NN_ + gn) * F + ch * 4]
                              : (float4){0.f, 0.f, 0.f, 0.f};
        bf16x4 bv = {(__bf16)v.x, (__bf16)v.y, (__bf16)v.z, (__bf16)v.w};
        *(bf16x4*)&hs[node * MS + ch * 4] = bv;
    }
    __syncthreads();

    const bf16x8* pw1v = (const bf16x8*)pw1;
    f32x4 accr[8], accc[8];
    #pragma unroll
    for (int m = 0; m < 8; m++) { accr[m] = (f32x4){0,0,0,0}; accc[m] = (f32x4){0,0,0,0}; }
    for (int kt = 0; kt < 4; kt++) {
        bf16x8 wr = pw1v[(wave * 9 + kt) * 64 + lane];       // We1 rows 0..127
        bf16x8 wc = pw1v[(wave * 9 + kt + 4) * 64 + lane];   // We1 rows 128..255
        #pragma unroll
        for (int m = 0; m < 8; m++) {
            bf16x8 x = *(const bf16x8*)&hs[(m * 16 + c) * MS + kt * 32 + quad * 8];
            accr[m] = __builtin_amdgcn_mfma_f32_16x16x32_bf16(wr, x, accr[m], 0, 0, 0);
            accc[m] = __builtin_amdgcn_mfma_f32_16x16x32_bf16(wc, x, accc[m], 0, 0, 0);
        }
    }
    #pragma unroll
    for (int m = 0; m < 8; m++) {
        int gn = n0 + m * 16 + c;
        if (gn < NN_) {
            size_t base = ((size_t)b * NN_ + gn) * F + wave * 16 + quad * 4;
            bf16x4 orr = {(__bf16)accr[m][0], (__bf16)accr[m][1], (__bf16)accr[m][2], (__bf16)accr[m][3]};
            bf16x4 occ = {(__bf16)accc[m][0], (__bf16)accc[m][1], (__bf16)accc[m][2], (__bf16)accc[m][3]};
            *(bf16x4*)&pr[base] = orr;
            *(bf16x4*)&pc[base] = occ;
        }
    }
}

// ------- edge kernel: presum + K=32 e1, MFMA chain, seg-reduce -------
__global__ __launch_bounds__(512, 4) void edge_kernel(
    const __bf16* __restrict__ pr, const __bf16* __restrict__ pc,
    const float* __restrict__ coord,
    const int* __restrict__ ei, const __bf16* __restrict__ eas,
    const int* __restrict__ bucket,
    const float* __restrict__ be1, const float* __restrict__ be2,
    const float* __restrict__ bc1,
    const __bf16* __restrict__ pw1, const __bf16* __restrict__ pw2,
    const __bf16* __restrict__ pwc1, const __bf16* __restrict__ pwc2,
    float* __restrict__ agg_h, float* __restrict__ agg_c)
{
    __shared__ __align__(16) __bf16 buf1[EDG * MS];  // presum -> h1 -> h2
    __shared__ __align__(16) __bf16 buf2[EDG * MS];  // xs32 (stride PS) -> ef
    __shared__ __bf16 cds[EDG][12];
    __shared__ int rs[EDG], cs[EDG];

    const int t = threadIdx.x;            // 0..511
    const int b = blockIdx.y;
    const int p0 = blockIdx.x * EDG;
    const int lane = t & 63, wave = t >> 6;
    const int quad = lane >> 4, c = lane & 15;
    const int mh = wave >> 2, np = wave & 3;

    if (t < EDG) {
        int eid = bucket[p0 + t];
        rs[t] = ei[eid]; cs[t] = ei[NE_ + eid];
    }
    __syncthreads();

    // ---- stage presum = pr[row] + pc[col] into buf1 ----
    const __bf16* prb = pr + (size_t)b * NN_ * F;
    const __bf16* pcb = pc + (size_t)b * NN_ * F;
    #pragma unroll
    for (int it = 0; it < 4; it++) {
        int idx = it * 512 + t;           // 0..2047: 128 edges x 16 chunks of 8
        int e = idx >> 4, ch = idx & 15;
        bf16x8 a = *(const bf16x8*)(prb + (size_t)rs[e] * F + ch * 8);
        bf16x8 v = *(const bf16x8*)(pcb + (size_t)cs[e] * F + ch * 8);
        bf16x8 o;
        #pragma unroll
        for (int j = 0; j < 8; j++) o[j] = (__bf16)((float)a[j] + (float)v[j]);
        *(bf16x8*)&buf1[e * MS + ch * 8] = o;
    }
    // ---- radial + ea -> xs32 (buf2 region, stride PS) ----
    if (t < EDG) {
        int e = t;
        const float* cr = coord + ((size_t)b * NN_ + rs[e]) * 12;
        const float* cc = coord + ((size_t)b * NN_ + cs[e]) * 12;
        float cd[12];
        #pragma unroll
        for (int j = 0; j < 12; j++) { cd[j] = cr[j] - cc[j]; cds[e][j] = (__bf16)cd[j]; }
        float prod[16]; float ss = 0.f;
        #pragma unroll
        for (int j = 0; j < 4; j++)
            #pragma unroll
            for (int k = 0; k < 4; k++) {
                float p = cd[j*3]*cd[k*3] + cd[j*3+1]*cd[k*3+1] + cd[j*3+2]*cd[k*3+2];
                prod[j*4 + k] = p; ss += p * p;
            }
        float inv = 1.0f / fmaxf(sqrtf(ss), 1e-12f);
        #pragma unroll
        for (int j = 0; j < 16; j++) buf2[e * PS + j] = (__bf16)(prod[j] * inv);
        const uint4* ep = (const uint4*)(eas + (size_t)(p0 + e) * 16);
        *(uint4*)&buf2[e * PS + 16] = ep[0];
        *(uint4*)&buf2[e * PS + 24] = ep[1];
    }
    __syncthreads();

    const bf16x8* pw1v  = (const bf16x8*)pw1;
    const bf16x8* pw2v  = (const bf16x8*)pw2;
    const bf16x8* pwc1v = (const bf16x8*)pwc1;
    const bf16x8* pwc2v = (const bf16x8*)pwc2;

    // ---- e1: K=32 (kt=8 of pw1) + presum + bias ----
    f32x4 acc1[4][2];
    #pragma unroll
    for (int m = 0; m < 4; m++)
        #pragma unroll
        for (int n = 0; n < 2; n++) acc1[m][n] = (f32x4){0,0,0,0};
    {
        bf16x8 x1[4];
        #pragma unroll
        for (int m = 0; m < 4; m++)
            x1[m] = *(const bf16x8*)&buf2[((mh*4 + m)*16 + c) * PS + quad*8];
        #pragma unroll
        for (int n = 0; n < 2; n++) {
            bf16x8 w = pw1v[((2*np + n)*9 + 8)*64 + lane];
            #pragma unroll
            for (int m = 0; m < 4; m++)
                acc1[m][n] = __builtin_amdgcn_mfma_f32_16x16x32_bf16(w, x1[m], acc1[m][n], 0, 0, 0);
        }
    }
    #pragma unroll
    for (int n = 0; n < 2; n++) {
        int nt = 2*np + n;
        float4 bb = *(const float4*)&be1[nt*16 + quad*4];
        #pragma unroll
        for (int m = 0; m < 4; m++) {
            int row = (mh*4 + m)*16 + c;
            bf16x4 p = *(const bf16x4*)&buf1[row * MS + nt*16 + quad*4];
            bf16x4 o = { (__bf16)fmaxf(acc1[m][n][0] + (float)p[0] + bb.x, 0.f),
                         (__bf16)fmaxf(acc1[m][n][1] + (float)p[1] + bb.y, 0.f),
                         (__bf16)fmaxf(acc1[m][n][2] + (float)p[2] + bb.z, 0.f),
                         (__bf16)fmaxf(acc1[m][n][3] + (float)p[3] + bb.w, 0.f) };
            *(bf16x4*)&buf1[row * MS + nt*16 + quad*4] = o;
        }
    }
    __syncthreads();

    // ---- e2: h1 @ We2 -> ef (buf2, stride MS) ----
    f32x4 acc2[4][2];
    #pragma unroll
    for (int m = 0; m < 4; m++)
        #pragma unroll
        for (int n = 0; n < 2; n++) acc2[m][n] = (f32x4){0,0,0,0};
    for (int kt = 0; kt < 4; kt++) {
        bf16x8 x[4];
        #pragma unroll
        for (int m = 0; m < 4; m++)
            x[m] = *(const bf16x8*)&buf1[((mh*4 + m)*16 + c) * MS + kt*32 + quad*8];
        #pragma unroll
        for (int n = 0; n < 2; n++) {
            bf16x8 w = pw2v[((2*np + n)*4 + kt)*64 + lane];
            #pragma unroll
            for (int m = 0; m < 4; m++)
                acc2[m][n] = __builtin_amdgcn_mfma_f32_16x16x32_bf16(w, x[m], acc2[m][n], 0, 0, 0);
        }
    }
    #pragma unroll
    for (int n = 0; n < 2; n++) {
        int nt = 2*np + n;
        float4 bb = *(const float4*)&be2[nt*16 + quad*4];
        #pragma unroll
        for (int m = 0; m < 4; m++) {
            int row = (mh*4 + m)*16 + c;
            bf16x4 o = { (__bf16)fmaxf(acc2[m][n][0] + bb.x, 0.f),
                         (__bf16)fmaxf(acc2[m][n][1] + bb.y, 0.f),
                         (__bf16)fmaxf(acc2[m][n][2] + bb.z, 0.f),
                         (__bf16)fmaxf(acc2[m][n][3] + bb.w, 0.f) };
            *(bf16x4*)&buf2[row * MS + nt*16 + quad*4] = o;
        }
    }
    __syncthreads();

    // ---- c1: ef @ Wc1 -> buf1 ----
    f32x4 acc3[4][2];
    #pragma unroll
    for (int m = 0; m < 4; m++)
        #pragma unroll
        for (int n = 0; n < 2; n++) acc3[m][n] = (f32x4){0,0,0,0};
    for (int kt = 0; kt < 4; kt++) {
        bf16x8 x[4];
        #pragma unroll
        for (int m = 0; m < 4; m++)
            x[m] = *(const bf16x8*)&buf2[((mh*4 + m)*16 + c) * MS + kt*32 + quad*8];
        #pragma unroll
        for (int n = 0; n < 2; n++) {
            bf16x8 w = pwc1v[((2*np + n)*4 + kt)*64 + lane];
            #pragma unroll
            for (int m = 0; m < 4; m++)
                acc3[m][n] = __builtin_amdgcn_mfma_f32_16x16x32_bf16(w, x[m], acc3[m][n], 0, 0, 0);
        }
    }
    #pragma unroll
    for (int n = 0; n < 2; n++) {
        int nt = 2*np + n;
        float4 bb = *(const float4*)&bc1[nt*16 + quad*4];
        #pragma unroll
        for (int m = 0; m < 4; m++) {
            int row = (mh*4 + m)*16 + c;
            bf16x4 o = { (__bf16)fmaxf(acc3[m][n][0] + bb.x, 0.f),
                         (__bf16)fmaxf(acc3[m][n][1] + bb.y, 0.f),
                         (__bf16)fmaxf(acc3[m][n][2] + bb.z, 0.f),
                         (__bf16)fmaxf(acc3[m][n][3] + bb.w, 0.f) };
            *(bf16x4*)&buf1[row * MS + nt*16 + quad*4] = o;
        }
    }
    __syncthreads();

    // ---- c2: wave owns edges wave*16..+15; valid feats in quad 0 ----
    f32x4 accw = (f32x4){0,0,0,0};
    for (int kt = 0; kt < 4; kt++) {
        bf16x8 x = *(const bf16x8*)&buf1[(wave*16 + c) * MS + kt*32 + quad*8];
        accw = __builtin_amdgcn_mfma_f32_16x16x32_bf16(pwc2v[kt*64 + lane], x, accw, 0, 0, 0);
    }
    if (quad == 0) {
        int e = wave*16 + c;
        #pragma unroll
        for (int j = 0; j < 12; j++)
            cds[e][j] = (__bf16)((float)cds[e][j] * accw[j/3]);
    }
    __syncthreads();

    // ---- segmented reduction over sorted rows -> few atomics ----
    {
        float* aggh_b = agg_h + (size_t)b * NN_ * HID;
        const int col = t & 127, seg = t >> 7;    // 4 segs x 32 edges
        float run = 0.f;
        int cur = rs[seg * 32];
        for (int e = seg * 32; e < seg * 32 + 32; e++) {
            int r = rs[e];
            float v = (float)buf2[e * MS + col];
            if (r != cur) {
                atomicAdd(&aggh_b[(size_t)cur * HID + col], run);
                run = 0.f; cur = r;
            }
            run += v;
        }
        atomicAdd(&aggh_b[(size_t)cur * HID + col], run);
    }
    if (t < 96) {
        float* aggc_b = agg_c + (size_t)b * NN_ * 12;
        const int j = t % 12, q = t / 12;         // 8 segs x 16 edges
        float run = 0.f;
        int cur = rs[q * 16];
        for (int e = q * 16; e < q * 16 + 16; e++) {
            int r = rs[e];
            float v = (float)cds[e][j];
            if (r != cur) {
                atomicAdd(&aggc_b[(size_t)cur * 12 + j], run);
                run = 0.f; cur = r;
            }
            run += v;
        }
        atomicAdd(&aggc_b[(size_t)cur * 12 + j], run);
    }
}

// ------- node kernel: MFMA bf16 MLP + residual + fused coord update -------
// 32 nodes/block, 256 threads (4 waves); wave -> nt pair {2w, 2w+1}, m in {0,1}
__global__ __launch_bounds__(256) void node_kernel(
    const float* __restrict__ h, const float* __restrict__ agg_h,
    const float* __restrict__ agg_c, const float* __restrict__ coord,
    const int* __restrict__ csr_off,
    const __bf16* __restrict__ pwn1, const float* __restrict__ bn1,
    const __bf16* __restrict__ pwn2, const float* __restrict__ bn2,
    float* __restrict__ out_h, float* __restrict__ out_c)
{
    __shared__ __align__(16) __bf16 zs[NPB2 * ZS];   // 16896 B; reused as os (fp32, stride 132)
    __shared__ __align__(16) __bf16 h1s[NPB2 * HS];  // 8704 B
    const int t = threadIdx.x;
    const int b = blockIdx.y;
    const int n0 = blockIdx.x * NPB2;
    const int lane = t & 63, wave = t >> 6;
    const int quad = lane >> 4, c = lane & 15;

    // stage z = [h | agg_h] bf16: 32 nodes x 64 float4-chunks
    #pragma unroll
    for (int it = 0; it < 8; it++) {
        int idx = it * 256 + t;              // 0..2047
        int node = idx >> 6, ch = idx & 63;  // ch 0..31 = h, 32..63 = agg_h
        int gn = n0 + node;
        float4 v = (float4){0.f, 0.f, 0.f, 0.f};
        if (gn < NN_) {
            const float* src = (ch < 32) ? &h[((size_t)b * NN_ + gn) * F + ch * 4]
                                         : &agg_h[((size_t)b * NN_ + gn) * HID + (ch - 32) * 4];
            v = *(const float4*)src;
        }
        bf16x4 bv = {(__bf16)v.x, (__bf16)v.y, (__bf16)v.z, (__bf16)v.w};
        *(bf16x4*)&zs[node * ZS + ch * 4] = bv;
    }
    __syncthreads();

    // L1: z(256) @ Wn1 -> relu -> h1s
    const bf16x8* w1v = (const bf16x8*)pwn1;
    const bf16x8* w2v = (const bf16x8*)pwn2;
    f32x4 a1[2][2];
    #pragma unroll
    for (int m = 0; m < 2; m++)
        #pragma unroll
        for (int n = 0; n < 2; n++) a1[m][n] = (f32x4){0,0,0,0};
    for (int kt = 0; kt < 8; kt++) {
        bf16x8 x[2];
        #pragma unroll
        for (int m = 0; m < 2; m++)
            x[m] = *(const bf16x8*)&zs[(m*16 + c) * ZS + kt*32 + quad*8];
        #pragma unroll
        for (int n = 0; n < 2; n++) {
            bf16x8 w = w1v[((2*wave + n)*8 + kt)*64 + lane];
            #pragma unroll
            for (int m = 0; m < 2; m++)
                a1[m][n] = __builtin_amdgcn_mfma_f32_16x16x32_bf16(w, x[m], a1[m][n], 0, 0, 0);
        }
    }
    __syncthreads();   // zs reads done (reused as os below)
    #pragma unroll
    for (int n = 0; n < 2; n++) {
        int nt = 2*wave + n;
        float4 bb = *(const float4*)&bn1[nt*16 + quad*4];
        #pragma unroll
        for (int m = 0; m < 2; m++) {
            bf16x4 o = { (__bf16)fmaxf(a1[m][n][0] + bb.x, 0.f),
                         (__bf16)fmaxf(a1[m][n][1] + bb.y, 0.f),
                         (__bf16)fmaxf(a1[m][n][2] + bb.z, 0.f),
                         (__bf16)fmaxf(a1[m][n][3] + bb.w, 0.f) };
            *(bf16x4*)&h1s[(m*16 + c) * HS + nt*16 + quad*4] = o;
        }
    }
    __syncthreads();

    // L2: h1(128) @ Wn2 -> +bn2 -> os (fp32, transpose via LDS)
    f32x4 a2[2][2];
    #pragma unroll
    for (int m = 0; m < 2; m++)
        #pragma unroll
        for (int n = 0; n < 2; n++) a2[m][n] = (f32x4){0,0,0,0};
    for (int kt = 0; kt < 4; kt++) {
        bf16x8 x[2];
        #pragma unroll
        for (int m = 0; m < 2; m++)
            x[m] = *(const bf16x8*)&h1s[(m*16 + c) * HS + kt*32 + quad*8];
        #pragma unroll
        for (int n = 0; n < 2; n++) {
            bf16x8 w = w2v[((2*wave + n)*4 + kt)*64 + lane];
            #pragma unroll
            for (int m = 0; m < 2; m++)
                a2[m][n] = __builtin_amdgcn_mfma_f32_16x16x32_bf16(w, x[m], a2[m][n], 0, 0, 0);
        }
    }
    float* os = (float*)zs;   // stride 132 floats
    #pragma unroll
    for (int n = 0; n < 2; n++) {
        int nt = 2*wave + n;
        float4 bb = *(const float4*)&bn2[nt*16 + quad*4];
        #pragma unroll
        for (int m = 0; m < 2; m++) {
            f32x4 o = { a2[m][n][0] + bb.x, a2[m][n][1] + bb.y,
                        a2[m][n][2] + bb.z, a2[m][n][3] + bb.w };
            *(f32x4*)&os[(m*16 + c) * 132 + nt*16 + quad*4] = o;
        }
    }
    __syncthreads();

    // coalesced residual write: 32 nodes x 32 float4
    #pragma unroll
    for (int it = 0; it < 4; it++) {
        int idx = it * 256 + t;              // 0..1023
        int node = idx >> 5, ch = idx & 31;
        int gn = n0 + node;
        if (gn < NN_) {
            size_t gb = ((size_t)b * NN_ + gn) * F + ch * 4;
            float4 hres = *(const float4*)&h[gb];
            float4 acc = *(const float4*)&os[node * 132 + ch * 4];
            float4 o = { hres.x + acc.x, hres.y + acc.y, hres.z + acc.z, hres.w + acc.w };
            *(float4*)&out_h[gb] = o;
        }
    }
    // fused coord update: 32 nodes x 12
    for (int idx = t; idx < NPB2 * 12; idx += 256) {
        int node = idx / 12, j = idx % 12;
        int gn = n0 + node;
        if (gn < NN_) {
            float deg = (float)(csr_off[gn + 1] - csr_off[gn]);
            size_t ci = ((size_t)b * NN_ + gn) * 12 + j;
            out_c[ci] = coord[ci] + agg_c[ci] / fmaxf(deg, 1.0f);
        }
    }
}

extern "C" void kernel_launch(void* const* d_in, const int* in_sizes, int n_in,
                              void* d_out, int out_size, void* d_ws, size_t ws_size,
                              hipStream_t stream) {
    const float* h     = (const float*)d_in[0];
    const float* coord = (const float*)d_in[1];
    const int*   ei    = (const int*)d_in[2];
    const float* ea    = (const float*)d_in[3];
    const float* We1   = (const float*)d_in[4];
    const float* be1   = (const float*)d_in[5];
    const float* We2   = (const float*)d_in[6];
    const float* be2   = (const float*)d_in[7];
    const float* Wn1   = (const float*)d_in[8];
    const float* bn1   = (const float*)d_in[9];
    const float* Wn2   = (const float*)d_in[10];
    const float* bn2   = (const float*)d_in[11];
    const float* Wc1   = (const float*)d_in[12];
    const float* bc1   = (const float*)d_in[13];
    const float* Wc2   = (const float*)d_in[14];

    float* out_h = (float*)d_out;                       // [B,N,F]
    float* out_c = out_h + (size_t)B * NN_ * F;         // [B,N,4,3]

    unsigned char* base = (unsigned char*)d_ws;
    __bf16* pw1  = (__bf16*)base;             // 36864 bf16
    __bf16* pw2  = pw1 + 36864;               // 16384
    __bf16* pwc1 = pw2 + 16384;               // 16384
    __bf16* pwc2 = pwc1 + 16384;              // 2048
    __bf16* pwn1 = pwc2 + 2048;               // 32768
    __bf16* pwn2 = pwn1 + 32768;              // 16384  -> 120832 elems = 241664 B
    unsigned char* dyn = base + 241664;

    int* csr_cnt = (int*)(dyn);               // 20000 B
    int* csr_off = (int*)(dyn + 20000);       // 20016 B
    int* csr_pos = (int*)(dyn + 40016);       // 20000 B
    int* bucket  = (int*)(dyn + 60016);       // 640000 B
    float* agg_h = (float*)(dyn + 700016);    // [B,N,HID]  5,120,000 B
    float* agg_c = agg_h + (size_t)B * NN_ * HID;      // [B,N,12] 480,000 B
    __bf16* pr   = (__bf16*)(agg_c + (size_t)B * NN_ * 12);  // 2,560,000 B
    __bf16* pc   = pr + (size_t)B * NN_ * F;                 // 2,560,000 B
    __bf16* eas  = pc + (size_t)B * NN_ * F;                 // 5,120,000 B

    pack_weights<<<472, 256, 0, stream>>>(We1, We2, Wc1, Wc2, Wn1, Wn2,
                                          pw1, pw2, pwc1, pwc2, pwn1, pwn2);

    hipMemsetAsync(csr_cnt, 0, 20000, stream);
    hipMemsetAsync(agg_h, 0, (size_t)B * NN_ * (HID + 12) * sizeof(float), stream);

    hist_kernel<<<625, 256, 0, stream>>>(ei, csr_cnt);
    scan_kernel<<<1, 256, 0, stream>>>(csr_cnt, csr_off, csr_pos);
    bucket_kernel<<<625, 256, 0, stream>>>(ei, ea, csr_pos, bucket, eas);

    dim3 pg((NN_ + 127) / 128, B);   // 40 x 2
    pre_kernel<<<pg, 512, 0, stream>>>(h, pw1, pr, pc);

    dim3 eg(NE_ / EDG, B);   // 1250 x 2
    edge_kernel<<<eg, 512, 0, stream>>>(pr, pc, coord, ei, eas, bucket, be1, be2, bc1,
                                        pw1, pw2, pwc1, pwc2, agg_h, agg_c);

    dim3 ng((NN_ + NPB2 - 1) / NPB2, B);   // 157 x 2
    node_kernel<<<ng, 256, 0, stream>>>(h, agg_h, agg_c, coord, csr_off,
                                        pwn1, bn1, pwn2, bn2, out_h, out_c);
}

// Round 9
// 203.918 us; speedup vs baseline: 2.0697x; 1.0224x over previous
//
#include <hip/hip_runtime.h>
#include <hip/hip_bf16.h>

#define B   2
#define NN_ 5000
#define NE_ 160000
#define F   128
#define HID 128
#define ED  16

typedef __bf16 bf16x8 __attribute__((ext_vector_type(8)));
typedef __bf16 bf16x4 __attribute__((ext_vector_type(4)));
typedef float  f32x4  __attribute__((ext_vector_type(4)));

#define MS  136   // edge buf row stride (17 16B-units, odd -> conflict-free b128)
#define PS  40    // xs32 row stride
#define EDG 128   // edges per block
#define ZS  264   // node z row stride bf16
#define HS  136   // node h1 row stride
#define NPB2 32   // nodes per block
#define NBUCKET 313  // bucket blocks in mid_kernel (313*512 >= NE_)

// ------ pack weights (+ zero agg/csr_cnt: replaces two memsets) ------
// frag: lane l holds W[k = kt*32 + (l>>4)*8 + j][n = nt*16 + (l&15)]; used as
// A-operand (W^T): D = W^T x X^T -> D[feat][edge] (col=edge, row=quad*4+i).
__global__ void pack_weights(const float* __restrict__ We1, const float* __restrict__ We2,
                             const float* __restrict__ Wc1, const float* __restrict__ Wc2,
                             const float* __restrict__ Wn1, const float* __restrict__ Wn2,
                             __bf16* __restrict__ pw1, __bf16* __restrict__ pw2,
                             __bf16* __restrict__ pwc1, __bf16* __restrict__ pwc2,
                             __bf16* __restrict__ pwn1, __bf16* __restrict__ pwn2,
                             float4* __restrict__ agg4, int* __restrict__ csr_cnt)
{
    int idx = blockIdx.x * 256 + threadIdx.x;   // 0 .. 120831
    const float* W; __bf16* P; int KT, Nr, local;
    if (idx < 36864)       { W = We1; P = pw1;  KT = 9; Nr = 128; local = idx; }
    else if (idx < 53248)  { W = We2; P = pw2;  KT = 4; Nr = 128; local = idx - 36864; }
    else if (idx < 69632)  { W = Wc1; P = pwc1; KT = 4; Nr = 128; local = idx - 53248; }
    else if (idx < 71680)  { W = Wc2; P = pwc2; KT = 4; Nr = 4;   local = idx - 69632; }
    else if (idx < 104448) { W = Wn1; P = pwn1; KT = 8; Nr = 128; local = idx - 71680; }
    else                   { W = Wn2; P = pwn2; KT = 4; Nr = 128; local = idx - 104448; }
    int j = local & 7, lane = (local >> 3) & 63, rest = local >> 9;
    int kt = rest % KT, nt = rest / KT;
    int k = kt * 32 + (lane >> 4) * 8 + j;
    int n = nt * 16 + (lane & 15);
    float v = (n < Nr) ? W[k * Nr + n] : 0.f;
    P[local] = (__bf16)v;

    // zero agg_h+agg_c (contiguous, 350000 float4) and csr_cnt
    float4 z4 = {0.f, 0.f, 0.f, 0.f};
    for (int i = idx; i < 350000; i += 120832) agg4[i] = z4;
    if (idx < NN_) csr_cnt[idx] = 0;
}

// ---------------- CSR build ----------------
__global__ void hist_kernel(const int* __restrict__ ei, int* __restrict__ csr_cnt)
{
    int i = blockIdx.x * 256 + threadIdx.x;
    if (i < NE_) atomicAdd(&csr_cnt[ei[i]], 1);
}

__global__ void scan_kernel(const int* __restrict__ csr_cnt,
                            int* __restrict__ csr_off, int* __restrict__ csr_pos)
{
    __shared__ int part[256];
    const int t = threadIdx.x;
    int sum = 0;
    #pragma unroll
    for (int j = 0; j < 20; j++) {
        int idx = t * 20 + j;
        if (idx < NN_) sum += csr_cnt[idx];
    }
    part[t] = sum;
    __syncthreads();
    if (t == 0) {
        int run = 0;
        for (int i = 0; i < 256; i++) { int v = part[i]; part[i] = run; run += v; }
    }
    __syncthreads();
    int run = part[t];
    #pragma unroll
    for (int j = 0; j < 20; j++) {
        int idx = t * 20 + j;
        if (idx < NN_) { csr_off[idx] = run; csr_pos[idx] = run; run += csr_cnt[idx]; }
    }
    if (t == 0) csr_off[NN_] = NE_;
}

// ------ mid kernel: bucket(+ea permute) blocks || pre (P_r/P_c GEMM) blocks ------
__global__ __launch_bounds__(512) void mid_kernel(
    const int* __restrict__ ei, const float* __restrict__ ea,
    int* __restrict__ csr_pos, int* __restrict__ bucket, __bf16* __restrict__ eas,
    const float* __restrict__ h, const __bf16* __restrict__ pw1,
    __bf16* __restrict__ pr, __bf16* __restrict__ pc)
{
    __shared__ __align__(16) __bf16 hs[128 * MS];
    const int t = threadIdx.x;

    if (blockIdx.x < NBUCKET) {
        // ---- bucket + sorted bf16 ea ----
        int i = blockIdx.x * 512 + t;
        if (i < NE_) {
            int p = atomicAdd(&csr_pos[ei[i]], 1);
            bucket[p] = i;
            const float4* src = (const float4*)(ea + (size_t)i * ED);
            __bf16* dst = eas + (size_t)p * ED;
            #pragma unroll
            for (int j = 0; j < 4; j++) {
                float4 v = src[j];
                bf16x4 bv = {(__bf16)v.x, (__bf16)v.y, (__bf16)v.z, (__bf16)v.w};
                *(bf16x4*)&dst[j * 4] = bv;
            }
        }
        return;
    }

    // ---- pre: per-node P_r = h @ We1[0:128], P_c = h @ We1[128:256] ----
    const int bp = blockIdx.x - NBUCKET;      // 0..79
    const int b = bp / 40;
    const int n0 = (bp % 40) * 128;
    const int lane = t & 63, wave = t >> 6;   // wave = nt (8 feat-tiles)
    const int quad = lane >> 4, c = lane & 15;

    #pragma unroll
    for (int it = 0; it < 8; it++) {
        int idx = it * 512 + t;               // 0..4095
        int node = idx >> 5, ch = idx & 31;
        int gn = n0 + node;
        float4 v = (gn < NN_) ? *(const float4*)&h[((size_t)b * NN_ + gn) * F + ch * 4]
                              : (float4){0.f, 0.f, 0.f, 0.f};
        bf16x4 bv = {(__bf16)v.x, (__bf16)v.y, (__bf16)v.z, (__bf16)v.w};
        *(bf16x4*)&hs[node * MS + ch * 4] = bv;
    }
    __syncthreads();

    const bf16x8* pw1v = (const bf16x8*)pw1;
    f32x4 accr[8], accc[8];
    #pragma unroll
    for (int m = 0; m < 8; m++) { accr[m] = (f32x4){0,0,0,0}; accc[m] = (f32x4){0,0,0,0}; }
    for (int kt = 0; kt < 4; kt++) {
        bf16x8 wr = pw1v[(wave * 9 + kt) * 64 + lane];       // We1 rows 0..127
        bf16x8 wc = pw1v[(wave * 9 + kt + 4) * 64 + lane];   // We1 rows 128..255
        #pragma unroll
        for (int m = 0; m < 8; m++) {
            bf16x8 x = *(const bf16x8*)&hs[(m * 16 + c) * MS + kt * 32 + quad * 8];
            accr[m] = __builtin_amdgcn_mfma_f32_16x16x32_bf16(wr, x, accr[m], 0, 0, 0);
            accc[m] = __builtin_amdgcn_mfma_f32_16x16x32_bf16(wc, x, accc[m], 0, 0, 0);
        }
    }
    #pragma unroll
    for (int m = 0; m < 8; m++) {
        int gn = n0 + m * 16 + c;
        if (gn < NN_) {
            size_t base = ((size_t)b * NN_ + gn) * F + wave * 16 + quad * 4;
            bf16x4 orr = {(__bf16)accr[m][0], (__bf16)accr[m][1], (__bf16)accr[m][2], (__bf16)accr[m][3]};
            bf16x4 occ = {(__bf16)accc[m][0], (__bf16)accc[m][1], (__bf16)accc[m][2], (__bf16)accc[m][3]};
            *(bf16x4*)&pr[base] = orr;
            *(bf16x4*)&pc[base] = occ;
        }
    }
}

// ------- edge kernel: presum + K=32 e1, MFMA chain, seg-reduce -------
__global__ __launch_bounds__(512, 4) void edge_kernel(
    const __bf16* __restrict__ pr, const __bf16* __restrict__ pc,
    const float* __restrict__ coord,
    const int* __restrict__ ei, const __bf16* __restrict__ eas,
    const int* __restrict__ bucket,
    const float* __restrict__ be1, const float* __restrict__ be2,
    const float* __restrict__ bc1,
    const __bf16* __restrict__ pw1, const __bf16* __restrict__ pw2,
    const __bf16* __restrict__ pwc1, const __bf16* __restrict__ pwc2,
    float* __restrict__ agg_h, float* __restrict__ agg_c)
{
    __shared__ __align__(16) __bf16 buf1[EDG * MS];  // presum -> h1 -> h2
    __shared__ __align__(16) __bf16 buf2[EDG * MS];  // xs32 (stride PS) -> ef
    __shared__ __bf16 cds[EDG][12];
    __shared__ int rs[EDG], cs[EDG];

    const int t = threadIdx.x;            // 0..511
    const int b = blockIdx.y;
    const int p0 = blockIdx.x * EDG;
    const int lane = t & 63, wave = t >> 6;
    const int quad = lane >> 4, c = lane & 15;
    const int mh = wave >> 2, np = wave & 3;

    if (t < EDG) {
        int eid = bucket[p0 + t];
        rs[t] = ei[eid]; cs[t] = ei[NE_ + eid];
    }
    __syncthreads();

    // ---- stage presum = pr[row] + pc[col] into buf1 ----
    const __bf16* prb = pr + (size_t)b * NN_ * F;
    const __bf16* pcb = pc + (size_t)b * NN_ * F;
    #pragma unroll
    for (int it = 0; it < 4; it++) {
        int idx = it * 512 + t;           // 0..2047: 128 edges x 16 chunks of 8
        int e = idx >> 4, ch = idx & 15;
        bf16x8 a = *(const bf16x8*)(prb + (size_t)rs[e] * F + ch * 8);
        bf16x8 v = *(const bf16x8*)(pcb + (size_t)cs[e] * F + ch * 8);
        bf16x8 o;
        #pragma unroll
        for (int j = 0; j < 8; j++) o[j] = (__bf16)((float)a[j] + (float)v[j]);
        *(bf16x8*)&buf1[e * MS + ch * 8] = o;
    }
    // ---- radial + ea -> xs32 (buf2 region, stride PS) ----
    if (t < EDG) {
        int e = t;
        const float* cr = coord + ((size_t)b * NN_ + rs[e]) * 12;
        const float* cc = coord + ((size_t)b * NN_ + cs[e]) * 12;
        float cd[12];
        #pragma unroll
        for (int j = 0; j < 12; j++) { cd[j] = cr[j] - cc[j]; cds[e][j] = (__bf16)cd[j]; }
        float prod[16]; float ss = 0.f;
        #pragma unroll
        for (int j = 0; j < 4; j++)
            #pragma unroll
            for (int k = 0; k < 4; k++) {
                float p = cd[j*3]*cd[k*3] + cd[j*3+1]*cd[k*3+1] + cd[j*3+2]*cd[k*3+2];
                prod[j*4 + k] = p; ss += p * p;
            }
        float inv = 1.0f / fmaxf(sqrtf(ss), 1e-12f);
        #pragma unroll
        for (int j = 0; j < 16; j++) buf2[e * PS + j] = (__bf16)(prod[j] * inv);
        const uint4* ep = (const uint4*)(eas + (size_t)(p0 + e) * 16);
        *(uint4*)&buf2[e * PS + 16] = ep[0];
        *(uint4*)&buf2[e * PS + 24] = ep[1];
    }
    __syncthreads();

    const bf16x8* pw1v  = (const bf16x8*)pw1;
    const bf16x8* pw2v  = (const bf16x8*)pw2;
    const bf16x8* pwc1v = (const bf16x8*)pwc1;
    const bf16x8* pwc2v = (const bf16x8*)pwc2;

    // ---- e1: K=32 (kt=8 of pw1) + presum + bias ----
    f32x4 acc1[4][2];
    #pragma unroll
    for (int m = 0; m < 4; m++)
        #pragma unroll
        for (int n = 0; n < 2; n++) acc1[m][n] = (f32x4){0,0,0,0};
    {
        bf16x8 x1[4];
        #pragma unroll
        for (int m = 0; m < 4; m++)
            x1[m] = *(const bf16x8*)&buf2[((mh*4 + m)*16 + c) * PS + quad*8];
        #pragma unroll
        for (int n = 0; n < 2; n++) {
            bf16x8 w = pw1v[((2*np + n)*9 + 8)*64 + lane];
            #pragma unroll
            for (int m = 0; m < 4; m++)
                acc1[m][n] = __builtin_amdgcn_mfma_f32_16x16x32_bf16(w, x1[m], acc1[m][n], 0, 0, 0);
        }
    }
    #pragma unroll
    for (int n = 0; n < 2; n++) {
        int nt = 2*np + n;
        float4 bb = *(const float4*)&be1[nt*16 + quad*4];
        #pragma unroll
        for (int m = 0; m < 4; m++) {
            int row = (mh*4 + m)*16 + c;
            bf16x4 p = *(const bf16x4*)&buf1[row * MS + nt*16 + quad*4];
            bf16x4 o = { (__bf16)fmaxf(acc1[m][n][0] + (float)p[0] + bb.x, 0.f),
                         (__bf16)fmaxf(acc1[m][n][1] + (float)p[1] + bb.y, 0.f),
                         (__bf16)fmaxf(acc1[m][n][2] + (float)p[2] + bb.z, 0.f),
                         (__bf16)fmaxf(acc1[m][n][3] + (float)p[3] + bb.w, 0.f) };
            *(bf16x4*)&buf1[row * MS + nt*16 + quad*4] = o;
        }
    }
    __syncthreads();

    // ---- e2: h1 @ We2 -> ef (buf2, stride MS) ----
    f32x4 acc2[4][2];
    #pragma unroll
    for (int m = 0; m < 4; m++)
        #pragma unroll
        for (int n = 0; n < 2; n++) acc2[m][n] = (f32x4){0,0,0,0};
    for (int kt = 0; kt < 4; kt++) {
        bf16x8 x[4];
        #pragma unroll
        for (int m = 0; m < 4; m++)
            x[m] = *(const bf16x8*)&buf1[((mh*4 + m)*16 + c) * MS + kt*32 + quad*8];
        #pragma unroll
        for (int n = 0; n < 2; n++) {
            bf16x8 w = pw2v[((2*np + n)*4 + kt)*64 + lane];
            #pragma unroll
            for (int m = 0; m < 4; m++)
                acc2[m][n] = __builtin_amdgcn_mfma_f32_16x16x32_bf16(w, x[m], acc2[m][n], 0, 0, 0);
        }
    }
    #pragma unroll
    for (int n = 0; n < 2; n++) {
        int nt = 2*np + n;
        float4 bb = *(const float4*)&be2[nt*16 + quad*4];
        #pragma unroll
        for (int m = 0; m < 4; m++) {
            int row = (mh*4 + m)*16 + c;
            bf16x4 o = { (__bf16)fmaxf(acc2[m][n][0] + bb.x, 0.f),
                         (__bf16)fmaxf(acc2[m][n][1] + bb.y, 0.f),
                         (__bf16)fmaxf(acc2[m][n][2] + bb.z, 0.f),
                         (__bf16)fmaxf(acc2[m][n][3] + bb.w, 0.f) };
            *(bf16x4*)&buf2[row * MS + nt*16 + quad*4] = o;
        }
    }
    __syncthreads();

    // ---- c1: ef @ Wc1 -> buf1 ----
    f32x4 acc3[4][2];
    #pragma unroll
    for (int m = 0; m < 4; m++)
        #pragma unroll
        for (int n = 0; n < 2; n++) acc3[m][n] = (f32x4){0,0,0,0};
    for (int kt = 0; kt < 4; kt++) {
        bf16x8 x[4];
        #pragma unroll
        for (int m = 0; m < 4; m++)
            x[m] = *(const bf16x8*)&buf2[((mh*4 + m)*16 + c) * MS + kt*32 + quad*8];
        #pragma unroll
        for (int n = 0; n < 2; n++) {
            bf16x8 w = pwc1v[((2*np + n)*4 + kt)*64 + lane];
            #pragma unroll
            for (int m = 0; m < 4; m++)
                acc3[m][n] = __builtin_amdgcn_mfma_f32_16x16x32_bf16(w, x[m], acc3[m][n], 0, 0, 0);
        }
    }
    #pragma unroll
    for (int n = 0; n < 2; n++) {
        int nt = 2*np + n;
        float4 bb = *(const float4*)&bc1[nt*16 + quad*4];
        #pragma unroll
        for (int m = 0; m < 4; m++) {
            int row = (mh*4 + m)*16 + c;
            bf16x4 o = { (__bf16)fmaxf(acc3[m][n][0] + bb.x, 0.f),
                         (__bf16)fmaxf(acc3[m][n][1] + bb.y, 0.f),
                         (__bf16)fmaxf(acc3[m][n][2] + bb.z, 0.f),
                         (__bf16)fmaxf(acc3[m][n][3] + bb.w, 0.f) };
            *(bf16x4*)&buf1[row * MS + nt*16 + quad*4] = o;
        }
    }
    __syncthreads();

    // ---- c2: wave owns edges wave*16..+15; valid feats in quad 0 ----
    f32x4 accw = (f32x4){0,0,0,0};
    for (int kt = 0; kt < 4; kt++) {
        bf16x8 x = *(const bf16x8*)&buf1[(wave*16 + c) * MS + kt*32 + quad*8];
        accw = __builtin_amdgcn_mfma_f32_16x16x32_bf16(pwc2v[kt*64 + lane], x, accw, 0, 0, 0);
    }
    if (quad == 0) {
        int e = wave*16 + c;
        #pragma unroll
        for (int j = 0; j < 12; j++)
            cds[e][j] = (__bf16)((float)cds[e][j] * accw[j/3]);
    }
    __syncthreads();

    // ---- segmented reduction over sorted rows (b32: 2 cols/thread, 16-edge segs) ----
    {
        float* aggh_b = agg_h + (size_t)b * NN_ * HID;
        const int cp = t & 63;        // col pair -> cols 2cp, 2cp+1
        const int seg = t >> 6;       // 8 segs x 16 edges
        float r0 = 0.f, r1 = 0.f;
        int cur = rs[seg * 16];
        for (int e = seg * 16; e < seg * 16 + 16; e++) {
            int r = rs[e];
            unsigned u = *(const unsigned*)&buf2[e * MS + cp * 2];
            float v0 = __uint_as_float(u << 16);
            float v1 = __uint_as_float(u & 0xffff0000u);
            if (r != cur) {
                atomicAdd(&aggh_b[(size_t)cur * HID + cp*2],     r0);
                atomicAdd(&aggh_b[(size_t)cur * HID + cp*2 + 1], r1);
                r0 = r1 = 0.f; cur = r;
            }
            r0 += v0; r1 += v1;
        }
        atomicAdd(&aggh_b[(size_t)cur * HID + cp*2],     r0);
        atomicAdd(&aggh_b[(size_t)cur * HID + cp*2 + 1], r1);
    }
    if (t < 96) {
        float* aggc_b = agg_c + (size_t)b * NN_ * 12;
        const int j = t % 12, q = t / 12;         // 8 segs x 16 edges
        float run = 0.f;
        int cur = rs[q * 16];
        for (int e = q * 16; e < q * 16 + 16; e++) {
            int r = rs[e];
            float v = (float)cds[e][j];
            if (r != cur) {
                atomicAdd(&aggc_b[(size_t)cur * 12 + j], run);
                run = 0.f; cur = r;
            }
            run += v;
        }
        atomicAdd(&aggc_b[(size_t)cur * 12 + j], run);
    }
}

// ------- node kernel: MFMA bf16 MLP + residual + fused coord update -------
__global__ __launch_bounds__(256) void node_kernel(
    const float* __restrict__ h, const float* __restrict__ agg_h,
    const float* __restrict__ agg_c, const float* __restrict__ coord,
    const int* __restrict__ csr_off,
    const __bf16* __restrict__ pwn1, const float* __restrict__ bn1,
    const __bf16* __restrict__ pwn2, const float* __restrict__ bn2,
    float* __restrict__ out_h, float* __restrict__ out_c)
{
    __shared__ __align__(16) __bf16 zs[NPB2 * ZS];   // reused as os (fp32, stride 132)
    __shared__ __align__(16) __bf16 h1s[NPB2 * HS];
    const int t = threadIdx.x;
    const int b = blockIdx.y;
    const int n0 = blockIdx.x * NPB2;
    const int lane = t & 63, wave = t >> 6;
    const int quad = lane >> 4, c = lane & 15;

    #pragma unroll
    for (int it = 0; it < 8; it++) {
        int idx = it * 256 + t;              // 0..2047
        int node = idx >> 6, ch = idx & 63;  // ch 0..31 = h, 32..63 = agg_h
        int gn = n0 + node;
        float4 v = (float4){0.f, 0.f, 0.f, 0.f};
        if (gn < NN_) {
            const float* src = (ch < 32) ? &h[((size_t)b * NN_ + gn) * F + ch * 4]
                                         : &agg_h[((size_t)b * NN_ + gn) * HID + (ch - 32) * 4];
            v = *(const float4*)src;
        }
        bf16x4 bv = {(__bf16)v.x, (__bf16)v.y, (__bf16)v.z, (__bf16)v.w};
        *(bf16x4*)&zs[node * ZS + ch * 4] = bv;
    }
    __syncthreads();

    const bf16x8* w1v = (const bf16x8*)pwn1;
    const bf16x8* w2v = (const bf16x8*)pwn2;
    f32x4 a1[2][2];
    #pragma unroll
    for (int m = 0; m < 2; m++)
        #pragma unroll
        for (int n = 0; n < 2; n++) a1[m][n] = (f32x4){0,0,0,0};
    for (int kt = 0; kt < 8; kt++) {
        bf16x8 x[2];
        #pragma unroll
        for (int m = 0; m < 2; m++)
            x[m] = *(const bf16x8*)&zs[(m*16 + c) * ZS + kt*32 + quad*8];
        #pragma unroll
        for (int n = 0; n < 2; n++) {
            bf16x8 w = w1v[((2*wave + n)*8 + kt)*64 + lane];
            #pragma unroll
            for (int m = 0; m < 2; m++)
                a1[m][n] = __builtin_amdgcn_mfma_f32_16x16x32_bf16(w, x[m], a1[m][n], 0, 0, 0);
        }
    }
    __syncthreads();
    #pragma unroll
    for (int n = 0; n < 2; n++) {
        int nt = 2*wave + n;
        float4 bb = *(const float4*)&bn1[nt*16 + quad*4];
        #pragma unroll
        for (int m = 0; m < 2; m++) {
            bf16x4 o = { (__bf16)fmaxf(a1[m][n][0] + bb.x, 0.f),
                         (__bf16)fmaxf(a1[m][n][1] + bb.y, 0.f),
                         (__bf16)fmaxf(a1[m][n][2] + bb.z, 0.f),
                         (__bf16)fmaxf(a1[m][n][3] + bb.w, 0.f) };
            *(bf16x4*)&h1s[(m*16 + c) * HS + nt*16 + quad*4] = o;
        }
    }
    __syncthreads();

    f32x4 a2[2][2];
    #pragma unroll
    for (int m = 0; m < 2; m++)
        #pragma unroll
        for (int n = 0; n < 2; n++) a2[m][n] = (f32x4){0,0,0,0};
    for (int kt = 0; kt < 4; kt++) {
        bf16x8 x[2];
        #pragma unroll
        for (int m = 0; m < 2; m++)
            x[m] = *(const bf16x8*)&h1s[(m*16 + c) * HS + kt*32 + quad*8];
        #pragma unroll
        for (int n = 0; n < 2; n++) {
            bf16x8 w = w2v[((2*wave + n)*4 + kt)*64 + lane];
            #pragma unroll
            for (int m = 0; m < 2; m++)
                a2[m][n] = __builtin_amdgcn_mfma_f32_16x16x32_bf16(w, x[m], a2[m][n], 0, 0, 0);
        }
    }
    float* os = (float*)zs;   // stride 132 floats
    #pragma unroll
    for (int n = 0; n < 2; n++) {
        int nt = 2*wave + n;
        float4 bb = *(const float4*)&bn2[nt*16 + quad*4];
        #pragma unroll
        for (int m = 0; m < 2; m++) {
            f32x4 o = { a2[m][n][0] + bb.x, a2[m][n][1] + bb.y,
                        a2[m][n][2] + bb.z, a2[m][n][3] + bb.w };
            *(f32x4*)&os[(m*16 + c) * 132 + nt*16 + quad*4] = o;
        }
    }
    __syncthreads();

    #pragma unroll
    for (int it = 0; it < 4; it++) {
        int idx = it * 256 + t;              // 0..1023
        int node = idx >> 5, ch = idx & 31;
        int gn = n0 + node;
        if (gn < NN_) {
            size_t gb = ((size_t)b * NN_ + gn) * F + ch * 4;
            float4 hres = *(const float4*)&h[gb];
            float4 acc = *(const float4*)&os[node * 132 + ch * 4];
            float4 o = { hres.x + acc.x, hres.y + acc.y, hres.z + acc.z, hres.w + acc.w };
            *(float4*)&out_h[gb] = o;
        }
    }
    for (int idx = t; idx < NPB2 * 12; idx += 256) {
        int node = idx / 12, j = idx % 12;
        int gn = n0 + node;
        if (gn < NN_) {
            float deg = (float)(csr_off[gn + 1] - csr_off[gn]);
            size_t ci = ((size_t)b * NN_ + gn) * 12 + j;
            out_c[ci] = coord[ci] + agg_c[ci] / fmaxf(deg, 1.0f);
        }
    }
}

extern "C" void kernel_launch(void* const* d_in, const int* in_sizes, int n_in,
                              void* d_out, int out_size, void* d_ws, size_t ws_size,
                              hipStream_t stream) {
    const float* h     = (const float*)d_in[0];
    const float* coord = (const float*)d_in[1];
    const int*   ei    = (const int*)d_in[2];
    const float* ea    = (const float*)d_in[3];
    const float* We1   = (const float*)d_in[4];
    const float* be1   = (const float*)d_in[5];
    const float* We2   = (const float*)d_in[6];
    const float* be2   = (const float*)d_in[7];
    const float* Wn1   = (const float*)d_in[8];
    const float* bn1   = (const float*)d_in[9];
    const float* Wn2   = (const float*)d_in[10];
    const float* bn2   = (const float*)d_in[11];
    const float* Wc1   = (const float*)d_in[12];
    const float* bc1   = (const float*)d_in[13];
    const float* Wc2   = (const float*)d_in[14];

    float* out_h = (float*)d_out;                       // [B,N,F]
    float* out_c = out_h + (size_t)B * NN_ * F;         // [B,N,4,3]

    unsigned char* base = (unsigned char*)d_ws;
    __bf16* pw1  = (__bf16*)base;             // 36864 bf16
    __bf16* pw2  = pw1 + 36864;               // 16384
    __bf16* pwc1 = pw2 + 16384;               // 16384
    __bf16* pwc2 = pwc1 + 16384;              // 2048
    __bf16* pwn1 = pwc2 + 2048;               // 32768
    __bf16* pwn2 = pwn1 + 32768;              // 16384  -> 120832 elems = 241664 B
    unsigned char* dyn = base + 241664;

    int* csr_cnt = (int*)(dyn);               // 20000 B
    int* csr_off = (int*)(dyn + 20000);       // 20016 B
    int* csr_pos = (int*)(dyn + 40016);       // 20000 B
    int* bucket  = (int*)(dyn + 60016);       // 640000 B
    float* agg_h = (float*)(dyn + 700016);    // [B,N,HID]  5,120,000 B
    float* agg_c = agg_h + (size_t)B * NN_ * HID;      // [B,N,12] 480,000 B
    __bf16* pr   = (__bf16*)(agg_c + (size_t)B * NN_ * 12);  // 2,560,000 B
    __bf16* pc   = pr + (size_t)B * NN_ * F;                 // 2,560,000 B
    __bf16* eas  = pc + (size_t)B * NN_ * F;                 // 5,120,000 B

    pack_weights<<<472, 256, 0, stream>>>(We1, We2, Wc1, Wc2, Wn1, Wn2,
                                          pw1, pw2, pwc1, pwc2, pwn1, pwn2,
                                          (float4*)agg_h, csr_cnt);

    hist_kernel<<<625, 256, 0, stream>>>(ei, csr_cnt);
    scan_kernel<<<1, 256, 0, stream>>>(csr_cnt, csr_off, csr_pos);

    mid_kernel<<<NBUCKET + 80, 512, 0, stream>>>(ei, ea, csr_pos, bucket, eas,
                                                 h, pw1, pr, pc);

    dim3 eg(NE_ / EDG, B);   // 1250 x 2
    edge_kernel<<<eg, 512, 0, stream>>>(pr, pc, coord, ei, eas, bucket, be1, be2, bc1,
                                        pw1, pw2, pwc1, pwc2, agg_h, agg_c);

    dim3 ng((NN_ + NPB2 - 1) / NPB2, B);   // 157 x 2
    node_kernel<<<ng, 256, 0, stream>>>(h, agg_h, agg_c, coord, csr_off,
                                        pwn1, bn1, pwn2, bn2, out_h, out_c);
}